// Round 2
// baseline (5599.479 us; speedup 1.0000x reference)
//
#include <hip/hip_runtime.h>

#define NP 100000
#define NE 1600000
#define SD 64      // STATE_DIM
#define HID 32
#define MSG 64

// MLP: [a(64) || b(64)] -> relu(128x32) -> relu(32x32) -> 32x64 linear
// Weight addresses are wave-uniform (pointer + loop-constant offsets) ->
// compiler emits scalar loads on the SMEM pipe, keeping VALU for FMAs.
__device__ __forceinline__ void mlp3_128(
    const float* a, const float* b,
    const float* __restrict__ W1, const float* __restrict__ B1,
    const float* __restrict__ W2, const float* __restrict__ B2,
    const float* __restrict__ W3, const float* __restrict__ B3,
    float out[MSG]) {
  float h1[HID];
#pragma unroll
  for (int j = 0; j < HID; ++j) h1[j] = B1[j];

  const float4* a4 = reinterpret_cast<const float4*>(a);
  const float4* b4 = reinterpret_cast<const float4*>(b);

  // rows 0..63 of W1 multiply a
#pragma unroll 4
  for (int i4 = 0; i4 < 16; ++i4) {
    float4 v = a4[i4];
    const float* wr = W1 + i4 * 4 * HID;
    float xv[4] = {v.x, v.y, v.z, v.w};
#pragma unroll
    for (int k = 0; k < 4; ++k)
#pragma unroll
      for (int j = 0; j < HID; ++j)
        h1[j] = fmaf(xv[k], wr[k * HID + j], h1[j]);
  }
  // rows 64..127 of W1 multiply b
#pragma unroll 4
  for (int i4 = 0; i4 < 16; ++i4) {
    float4 v = b4[i4];
    const float* wr = W1 + (64 + i4 * 4) * HID;
    float xv[4] = {v.x, v.y, v.z, v.w};
#pragma unroll
    for (int k = 0; k < 4; ++k)
#pragma unroll
      for (int j = 0; j < HID; ++j)
        h1[j] = fmaf(xv[k], wr[k * HID + j], h1[j]);
  }

  // layer 2: 32 -> 32
  float h2[HID];
#pragma unroll
  for (int j = 0; j < HID; ++j) h2[j] = B2[j];
#pragma unroll 8
  for (int i = 0; i < HID; ++i) {
    float hi = fmaxf(h1[i], 0.0f);
    const float* wr = W2 + i * HID;
#pragma unroll
    for (int j = 0; j < HID; ++j) h2[j] = fmaf(hi, wr[j], h2[j]);
  }

  // layer 3: 32 -> 64 (linear)
#pragma unroll
  for (int j = 0; j < MSG; ++j) out[j] = B3[j];
#pragma unroll 4
  for (int i = 0; i < HID; ++i) {
    float hi = fmaxf(h2[i], 0.0f);
    const float* wr = W3 + i * MSG;
#pragma unroll
    for (int j = 0; j < MSG; ++j) out[j] = fmaf(hi, wr[j], out[j]);
  }
}

__global__ __launch_bounds__(256, 4) void edge_msg_kernel(
    const float* __restrict__ x, const int* __restrict__ ei,
    const float* __restrict__ W1, const float* __restrict__ B1,
    const float* __restrict__ W2, const float* __restrict__ B2,
    const float* __restrict__ W3, const float* __restrict__ B3,
    float* msg) {
  int e = blockIdx.x * 256 + threadIdx.x;
  if (e >= NE) return;
  int src = ei[e];        // harness passes integer inputs as int32
  int dst = ei[NE + e];

  float m[MSG];
  mlp3_128(x + src * SD, x + dst * SD, W1, B1, W2, B2, W3, B3, m);

  float* mrow = msg + dst * MSG;
#pragma unroll
  for (int j = 0; j < MSG; ++j)
    __hip_atomic_fetch_add(mrow + j, m[j], __ATOMIC_RELAXED,
                           __HIP_MEMORY_SCOPE_AGENT);
}

__global__ __launch_bounds__(256, 4) void node_kernel(
    const float* __restrict__ x, const float* msg,
    const float* __restrict__ W1, const float* __restrict__ B1,
    const float* __restrict__ W2, const float* __restrict__ B2,
    const float* __restrict__ W3, const float* __restrict__ B3,
    float* out) {
  int n = blockIdx.x * 256 + threadIdx.x;
  if (n >= NP) return;

  float o[MSG];
  mlp3_128(x + n * SD, msg + n * MSG, W1, B1, W2, B2, W3, B3, o);

  float4* orow = reinterpret_cast<float4*>(out + n * MSG);
#pragma unroll
  for (int j4 = 0; j4 < 16; ++j4)
    orow[j4] = make_float4(o[4 * j4], o[4 * j4 + 1], o[4 * j4 + 2],
                           o[4 * j4 + 3]);
}

extern "C" void kernel_launch(void* const* d_in, const int* in_sizes, int n_in,
                              void* d_out, int out_size, void* d_ws,
                              size_t ws_size, hipStream_t stream) {
  const float* x = (const float*)d_in[0];
  const int* ei = (const int*)d_in[1];
  const float* mW1 = (const float*)d_in[2];
  const float* mb1 = (const float*)d_in[3];
  const float* mW2 = (const float*)d_in[4];
  const float* mb2 = (const float*)d_in[5];
  const float* mW3 = (const float*)d_in[6];
  const float* mb3 = (const float*)d_in[7];
  const float* oW1 = (const float*)d_in[8];
  const float* ob1 = (const float*)d_in[9];
  const float* oW2 = (const float*)d_in[10];
  const float* ob2 = (const float*)d_in[11];
  const float* oW3 = (const float*)d_in[12];
  const float* ob3 = (const float*)d_in[13];
  float* out = (float*)d_out;

  const size_t msg_bytes = (size_t)NP * MSG * sizeof(float);
  float* msg = (ws_size >= msg_bytes) ? (float*)d_ws : out;

  hipMemsetAsync(msg, 0, msg_bytes, stream);

  edge_msg_kernel<<<(NE + 255) / 256, 256, 0, stream>>>(
      x, ei, mW1, mb1, mW2, mb2, mW3, mb3, msg);

  node_kernel<<<(NP + 255) / 256, 256, 0, stream>>>(
      x, msg, oW1, ob1, oW2, ob2, oW3, ob3, out);
}

// Round 3
// 1429.925 us; speedup vs baseline: 3.9159x; 3.9159x over previous
//
#include <hip/hip_runtime.h>

#define NP 100000
#define NE 1600000
#define SD 64      // STATE_DIM
#define HID 32
#define MSG 64
#define NP_PAD 100352            // NP rounded up to 256
#define SCAN_B 256
#define NBLK ((NP + SCAN_B - 1) / SCAN_B)   // 391

// ---------------- CSR build ----------------

__global__ void hist_kernel(const int* __restrict__ ei, int* __restrict__ counts) {
  int e = blockIdx.x * 256 + threadIdx.x;
  if (e >= NE) return;
  atomicAdd(&counts[ei[NE + e]], 1);
}

// per-block exclusive scan of counts -> offsets, block totals -> bsums
__global__ void scan1_kernel(const int* __restrict__ counts,
                             int* __restrict__ offsets, int* __restrict__ bsums) {
  __shared__ int s[SCAN_B];
  int t = threadIdx.x;
  int i = blockIdx.x * SCAN_B + t;
  int v = (i < NP) ? counts[i] : 0;
  s[t] = v;
  __syncthreads();
  for (int off = 1; off < SCAN_B; off <<= 1) {
    int a = (t >= off) ? s[t - off] : 0;
    __syncthreads();
    s[t] += a;
    __syncthreads();
  }
  if (i < NP) offsets[i] = s[t] - v;            // exclusive
  if (t == SCAN_B - 1) bsums[blockIdx.x] = s[t]; // block total
}

// exclusive scan of the 391 block sums (single block of 512)
__global__ void scan2_kernel(int* __restrict__ bsums) {
  __shared__ int s[512];
  int t = threadIdx.x;
  int v = (t < NBLK) ? bsums[t] : 0;
  s[t] = v;
  __syncthreads();
  for (int off = 1; off < 512; off <<= 1) {
    int a = (t >= off) ? s[t - off] : 0;
    __syncthreads();
    s[t] += a;
    __syncthreads();
  }
  if (t < NBLK) bsums[t] = s[t] - v;            // exclusive
}

// add block base; also init cursor
__global__ void scan3_kernel(int* __restrict__ offsets,
                             const int* __restrict__ bsums,
                             int* __restrict__ cursor) {
  int i = blockIdx.x * SCAN_B + threadIdx.x;
  if (i >= NP) return;
  int o = offsets[i] + bsums[blockIdx.x];
  offsets[i] = o;
  cursor[i] = o;
}

// scatter src indices grouped by dst
__global__ void scatter_kernel(const int* __restrict__ ei,
                               int* __restrict__ cursor, int* __restrict__ csr_src) {
  int e = blockIdx.x * 256 + threadIdx.x;
  if (e >= NE) return;
  int src = ei[e];
  int dst = ei[NE + e];
  int pos = atomicAdd(&cursor[dst], 1);
  csr_src[pos] = src;
}

// ---------------- fused aggregate + node update ----------------
// Per node: h1d = mb1 + mW1[64:128]^T x_dst (once); per incident edge:
// h1 = h1d + mW1[0:64]^T x_src -> relu -> h2 -> relu -> acc += h2r @ mW3.
// acc init = cnt * mb3 (bias per message). Then own-state MLP on [x||acc].
__global__ __launch_bounds__(256, 2) void fused_node_kernel(
    const float* __restrict__ x,
    const int* __restrict__ offsets, const int* __restrict__ counts,
    const int* __restrict__ csr_src,
    const float* __restrict__ mW1, const float* __restrict__ mb1,
    const float* __restrict__ mW2, const float* __restrict__ mb2,
    const float* __restrict__ mW3, const float* __restrict__ mb3,
    const float* __restrict__ oW1, const float* __restrict__ ob1,
    const float* __restrict__ oW2, const float* __restrict__ ob2,
    const float* __restrict__ oW3, const float* __restrict__ ob3,
    float* __restrict__ out) {
  int n = blockIdx.x * 256 + threadIdx.x;
  if (n >= NP) return;

  const float4* xd4 = reinterpret_cast<const float4*>(x + (size_t)n * SD);

  // dst-half of message layer 1, amortized over all incident edges
  float h1d[HID];
#pragma unroll
  for (int j = 0; j < HID; ++j) h1d[j] = mb1[j];
#pragma unroll 4
  for (int i4 = 0; i4 < 16; ++i4) {
    float4 v = xd4[i4];
    const float* wr = mW1 + (64 + i4 * 4) * HID;
    float xv[4] = {v.x, v.y, v.z, v.w};
#pragma unroll
    for (int k = 0; k < 4; ++k)
#pragma unroll
      for (int j = 0; j < HID; ++j)
        h1d[j] = fmaf(xv[k], wr[k * HID + j], h1d[j]);
  }

  int beg = offsets[n];
  int cnt = counts[n];

  float acc[MSG];
  float fc = (float)cnt;
#pragma unroll
  for (int j = 0; j < MSG; ++j) acc[j] = fc * mb3[j];

  for (int t = 0; t < cnt; ++t) {
    int s = csr_src[beg + t];
    const float4* xs4 = reinterpret_cast<const float4*>(x + (size_t)s * SD);

    float h1[HID];
#pragma unroll
    for (int j = 0; j < HID; ++j) h1[j] = h1d[j];
#pragma unroll 4
    for (int i4 = 0; i4 < 16; ++i4) {
      float4 v = xs4[i4];
      const float* wr = mW1 + i4 * 4 * HID;
      float xv[4] = {v.x, v.y, v.z, v.w};
#pragma unroll
      for (int k = 0; k < 4; ++k)
#pragma unroll
        for (int j = 0; j < HID; ++j)
          h1[j] = fmaf(xv[k], wr[k * HID + j], h1[j]);
    }

    float h2[HID];
#pragma unroll
    for (int j = 0; j < HID; ++j) h2[j] = mb2[j];
#pragma unroll 8
    for (int i = 0; i < HID; ++i) {
      float hi = fmaxf(h1[i], 0.0f);
      const float* wr = mW2 + i * HID;
#pragma unroll
      for (int j = 0; j < HID; ++j) h2[j] = fmaf(hi, wr[j], h2[j]);
    }

#pragma unroll 4
    for (int i = 0; i < HID; ++i) {
      float hi = fmaxf(h2[i], 0.0f);
      const float* wr = mW3 + i * MSG;
#pragma unroll
      for (int j = 0; j < MSG; ++j) acc[j] = fmaf(hi, wr[j], acc[j]);
    }
  }

  // own-state MLP on [x_dst(64) || acc(64)]
  float g1[HID];
#pragma unroll
  for (int j = 0; j < HID; ++j) g1[j] = ob1[j];
#pragma unroll 4
  for (int i4 = 0; i4 < 16; ++i4) {
    float4 v = xd4[i4];   // L1/L2 hit, re-read to save registers
    const float* wr = oW1 + i4 * 4 * HID;
    float xv[4] = {v.x, v.y, v.z, v.w};
#pragma unroll
    for (int k = 0; k < 4; ++k)
#pragma unroll
      for (int j = 0; j < HID; ++j)
        g1[j] = fmaf(xv[k], wr[k * HID + j], g1[j]);
  }
#pragma unroll 4
  for (int i = 0; i < MSG; ++i) {
    const float* wr = oW1 + (64 + i) * HID;
    float ai = acc[i];
#pragma unroll
    for (int j = 0; j < HID; ++j) g1[j] = fmaf(ai, wr[j], g1[j]);
  }

  float g2[HID];
#pragma unroll
  for (int j = 0; j < HID; ++j) g2[j] = ob2[j];
#pragma unroll 8
  for (int i = 0; i < HID; ++i) {
    float gi = fmaxf(g1[i], 0.0f);
    const float* wr = oW2 + i * HID;
#pragma unroll
    for (int j = 0; j < HID; ++j) g2[j] = fmaf(gi, wr[j], g2[j]);
  }

  float o[SD];
#pragma unroll
  for (int j = 0; j < SD; ++j) o[j] = ob3[j];
#pragma unroll 4
  for (int i = 0; i < HID; ++i) {
    float gi = fmaxf(g2[i], 0.0f);
    const float* wr = oW3 + i * SD;
#pragma unroll
    for (int j = 0; j < SD; ++j) o[j] = fmaf(gi, wr[j], o[j]);
  }

  float4* orow = reinterpret_cast<float4*>(out + (size_t)n * SD);
#pragma unroll
  for (int j4 = 0; j4 < 16; ++j4)
    orow[j4] = make_float4(o[4 * j4], o[4 * j4 + 1], o[4 * j4 + 2], o[4 * j4 + 3]);
}

extern "C" void kernel_launch(void* const* d_in, const int* in_sizes, int n_in,
                              void* d_out, int out_size, void* d_ws,
                              size_t ws_size, hipStream_t stream) {
  const float* x = (const float*)d_in[0];
  const int* ei = (const int*)d_in[1];
  const float* mW1 = (const float*)d_in[2];
  const float* mb1 = (const float*)d_in[3];
  const float* mW2 = (const float*)d_in[4];
  const float* mb2 = (const float*)d_in[5];
  const float* mW3 = (const float*)d_in[6];
  const float* mb3 = (const float*)d_in[7];
  const float* oW1 = (const float*)d_in[8];
  const float* ob1 = (const float*)d_in[9];
  const float* oW2 = (const float*)d_in[10];
  const float* ob2 = (const float*)d_in[11];
  const float* oW3 = (const float*)d_in[12];
  const float* ob3 = (const float*)d_in[13];
  float* out = (float*)d_out;

  // workspace layout (ints): counts | offsets | cursor | bsums(512) | csr_src
  int* counts = (int*)d_ws;
  int* offsets = counts + NP_PAD;
  int* cursor = offsets + NP_PAD;
  int* bsums = cursor + NP_PAD;
  int* csr_src = bsums + 512;

  hipMemsetAsync(counts, 0, NP_PAD * sizeof(int), stream);

  hist_kernel<<<(NE + 255) / 256, 256, 0, stream>>>(ei, counts);
  scan1_kernel<<<NBLK, SCAN_B, 0, stream>>>(counts, offsets, bsums);
  scan2_kernel<<<1, 512, 0, stream>>>(bsums);
  scan3_kernel<<<NBLK, SCAN_B, 0, stream>>>(offsets, bsums, cursor);
  scatter_kernel<<<(NE + 255) / 256, 256, 0, stream>>>(ei, cursor, csr_src);

  fused_node_kernel<<<NBLK, 256, 0, stream>>>(
      x, offsets, counts, csr_src,
      mW1, mb1, mW2, mb2, mW3, mb3,
      oW1, ob1, oW2, ob2, oW3, ob3, out);
}

// Round 5
// 611.555 us; speedup vs baseline: 9.1561x; 2.3382x over previous
//
#include <hip/hip_runtime.h>

#define NP 100000
#define NE 1600000
#define SD 64      // STATE_DIM
#define HID 32
#define MSG 64
#define NP_PAD 100352
#define SCAN_B 256
#define NBLK ((NP + SCAN_B - 1) / SCAN_B)   // 391

typedef float v4f __attribute__((ext_vector_type(4)));
typedef short v8s __attribute__((ext_vector_type(8)));
typedef __bf16 v8bf __attribute__((ext_vector_type(8)));

__device__ __forceinline__ v4f MFMA32(v8s a, v8s b, v4f c) {
  return __builtin_amdgcn_mfma_f32_16x16x32_bf16(
      __builtin_bit_cast(v8bf, a), __builtin_bit_cast(v8bf, b), c, 0, 0, 0);
}

__device__ __forceinline__ short f2bf(float f) {
  unsigned u = __builtin_bit_cast(unsigned, f);
  u += 0x7FFFu + ((u >> 16) & 1u);   // RNE
  return (short)(u >> 16);
}
__device__ __forceinline__ float bf2f(short s) {
  unsigned u = ((unsigned)(unsigned short)s) << 16;
  return __builtin_bit_cast(float, u);
}

// 3-term split-bf16 product: C += Ah*Bh + Ah*Bl + Al*Bh  (error ~2^-17 rel)
__device__ __forceinline__ v4f mfma3(v8s ah, v8s al, v8s bh, v8s bl, v4f c) {
  c = MFMA32(al, bh, c);
  c = MFMA32(ah, bl, c);
  c = MFMA32(ah, bh, c);
  return c;
}

// A-frag (hi/lo) from row-major W[K][ld]: A[m][k] = W[k][m0+l15],
// elem j<4: k = kb + 4*lq + j ; j>=4: k = kb + 16 + 4*lq + (j-4)
__device__ __forceinline__ void load_wfrag(const float* __restrict__ W, int ld,
                                           int kb, int m0, int lq, int l15,
                                           v8s* hi, v8s* lo) {
  v8s h, l;
#pragma unroll
  for (int j = 0; j < 8; ++j) {
    int k = kb + ((j < 4) ? (4 * lq + j) : (16 + 4 * lq + (j - 4)));
    float v = W[k * ld + m0 + l15];
    short hb = f2bf(v);
    h[j] = hb;
    l[j] = f2bf(v - bf2f(hb));
  }
  *hi = h;
  *lo = l;
}

// B-frag (hi/lo) from a feature row: elem j<4 <- xs[kb+4lq+j], j>=4 <- xs[kb+16+4lq+j-4]
__device__ __forceinline__ void load_xfrag(const float* xs, int kb, int lq,
                                           v8s* hi, v8s* lo) {
  v4f a = *reinterpret_cast<const v4f*>(xs + kb + 4 * lq);
  v4f b = *reinterpret_cast<const v4f*>(xs + kb + 16 + 4 * lq);
  v8s h, l;
#pragma unroll
  for (int j = 0; j < 4; ++j) {
    short ha = f2bf(a[j]); h[j] = ha; l[j] = f2bf(a[j] - bf2f(ha));
    short hb = f2bf(b[j]); h[j + 4] = hb; l[j + 4] = f2bf(b[j] - bf2f(hb));
  }
  *hi = h;
  *lo = l;
}

// D-blocks (units 0..15 | 16..31) -> next-layer B-frag with relu, hi/lo.
// D reg q at lane(lq,l15) = D[4lq+q][l15]; B elem j needs k=4lq+j (j<4), 16+4lq+j-4 (j>=4).
__device__ __forceinline__ void chain_frag(v4f d0, v4f d1, v8s* hi, v8s* lo) {
  v8s h, l;
#pragma unroll
  for (int j = 0; j < 4; ++j) {
    float v0 = fmaxf(d0[j], 0.f);
    float v1 = fmaxf(d1[j], 0.f);
    short h0 = f2bf(v0); h[j] = h0;     l[j] = f2bf(v0 - bf2f(h0));
    short h1 = f2bf(v1); h[j + 4] = h1; l[j + 4] = f2bf(v1 - bf2f(h1));
  }
  *hi = h;
  *lo = l;
}

// ---------------- CSR build (proven in R3) ----------------

__global__ void hist_kernel(const int* __restrict__ ei, int* __restrict__ counts) {
  int e = blockIdx.x * 256 + threadIdx.x;
  if (e >= NE) return;
  atomicAdd(&counts[ei[NE + e]], 1);
}

__global__ void scan1_kernel(const int* __restrict__ counts,
                             int* __restrict__ offsets, int* __restrict__ bsums) {
  __shared__ int s[SCAN_B];
  int t = threadIdx.x;
  int i = blockIdx.x * SCAN_B + t;
  int v = (i < NP) ? counts[i] : 0;
  s[t] = v;
  __syncthreads();
  for (int off = 1; off < SCAN_B; off <<= 1) {
    int a = (t >= off) ? s[t - off] : 0;
    __syncthreads();
    s[t] += a;
    __syncthreads();
  }
  if (i < NP) offsets[i] = s[t] - v;
  if (t == SCAN_B - 1) bsums[blockIdx.x] = s[t];
}

__global__ void scan2_kernel(int* __restrict__ bsums) {
  __shared__ int s[512];
  int t = threadIdx.x;
  int v = (t < NBLK) ? bsums[t] : 0;
  s[t] = v;
  __syncthreads();
  for (int off = 1; off < 512; off <<= 1) {
    int a = (t >= off) ? s[t - off] : 0;
    __syncthreads();
    s[t] += a;
    __syncthreads();
  }
  if (t < NBLK) bsums[t] = s[t] - v;
}

__global__ void scan3_kernel(int* __restrict__ offsets,
                             const int* __restrict__ bsums,
                             int* __restrict__ cursor) {
  int i = blockIdx.x * SCAN_B + threadIdx.x;
  if (i >= NP) return;
  int o = offsets[i] + bsums[blockIdx.x];
  offsets[i] = o;
  cursor[i] = o;
}

__global__ void scatter_kernel(const int* __restrict__ ei,
                               int* __restrict__ cursor, int* __restrict__ csr_src) {
  int e = blockIdx.x * 256 + threadIdx.x;
  if (e >= NE) return;
  int src = ei[e];
  int dst = ei[NE + e];
  int pos = atomicAdd(&cursor[dst], 1);
  csr_src[pos] = src;
}

// ---------------- edge messages: swapped-operand MFMA, split-bf16 ----------------
__global__ __launch_bounds__(256, 1) void edge_mfma_kernel(
    const float* __restrict__ x, const int* __restrict__ counts,
    const int* __restrict__ offsets, const int* __restrict__ csr_src,
    const float* __restrict__ mW1, const float* __restrict__ mb1,
    const float* __restrict__ mW2, const float* __restrict__ mb2,
    const float* __restrict__ mW3, const float* __restrict__ mb3,
    float* __restrict__ msg) {
  const int l15 = threadIdx.x & 15;
  const int lq = (threadIdx.x & 63) >> 4;
  const int wid = (blockIdx.x * 256 + threadIdx.x) >> 6;
  const int nw = gridDim.x * 4;

  // weight A-frags: [t = unit-block][kc = feature-chunk]
  v8s w1sh[2][2], w1sl[2][2], w1dh[2][2], w1dl[2][2];
#pragma unroll
  for (int t = 0; t < 2; ++t)
#pragma unroll
    for (int kc = 0; kc < 2; ++kc) {
      load_wfrag(mW1, HID, kc * 32, t * 16, lq, l15, &w1sh[t][kc], &w1sl[t][kc]);
      load_wfrag(mW1, HID, 64 + kc * 32, t * 16, lq, l15, &w1dh[t][kc], &w1dl[t][kc]);
    }
  v8s w2h[2], w2l[2], w3h[4], w3l[4];
#pragma unroll
  for (int t = 0; t < 2; ++t)
    load_wfrag(mW2, HID, 0, t * 16, lq, l15, &w2h[t], &w2l[t]);
#pragma unroll
  for (int t = 0; t < 4; ++t)
    load_wfrag(mW3, MSG, 0, t * 16, lq, l15, &w3h[t], &w3l[t]);

  const v8s zz = {0, 0, 0, 0, 0, 0, 0, 0};

  for (int n = wid; n < NP; n += nw) {
    int cnt = counts[n];
    int off = offsets[n];
    const float* xn = x + (size_t)n * SD;

    // dst-half of layer 1 + bias, once per node (broadcast across slot-columns).
    // NOTE: x pointer uses feature index kc*32+..., the +64 lives ONLY in W1 rows.
    v4f h1d[2];
#pragma unroll
    for (int t = 0; t < 2; ++t)
      h1d[t] = *reinterpret_cast<const v4f*>(mb1 + t * 16 + 4 * lq);
#pragma unroll
    for (int kc = 0; kc < 2; ++kc) {
      v8s xh, xl;
      load_xfrag(xn, kc * 32, lq, &xh, &xl);
#pragma unroll
      for (int t = 0; t < 2; ++t)
        h1d[t] = mfma3(w1dh[t][kc], w1dl[t][kc], xh, xl, h1d[t]);
    }

    v4f macc[4];
#pragma unroll
    for (int t = 0; t < 4; ++t) macc[t] = (v4f){0.f, 0.f, 0.f, 0.f};

    int ng = (cnt + 15) >> 4;
    for (int g = 0; g < ng; ++g) {
      int rem = cnt - g * 16;
      bool valid = l15 < rem;
      int s = valid ? csr_src[off + g * 16 + l15] : n;
      const float* xs = x + (size_t)s * SD;

      v4f d0 = h1d[0], d1 = h1d[1];
#pragma unroll
      for (int kc = 0; kc < 2; ++kc) {
        v8s xh, xl;
        load_xfrag(xs, kc * 32, lq, &xh, &xl);
        d0 = mfma3(w1sh[0][kc], w1sl[0][kc], xh, xl, d0);
        d1 = mfma3(w1sh[1][kc], w1sl[1][kc], xh, xl, d1);
      }

      v8s ph, pl;
      chain_frag(d0, d1, &ph, &pl);
      v4f e0 = *reinterpret_cast<const v4f*>(mb2 + 4 * lq);
      v4f e1 = *reinterpret_cast<const v4f*>(mb2 + 16 + 4 * lq);
      e0 = mfma3(w2h[0], w2l[0], ph, pl, e0);
      e1 = mfma3(w2h[1], w2l[1], ph, pl, e1);

      v8s rh, rl;
      chain_frag(e0, e1, &rh, &rl);
      if (!valid) { rh = zz; rl = zz; }   // zero pad-slot columns
#pragma unroll
      for (int t = 0; t < 4; ++t)
        macc[t] = mfma3(w3h[t], w3l[t], rh, rl, macc[t]);
    }

    // sum over slot-columns: reduce across l15 (bits 0..3) within each lq group
#pragma unroll
    for (int t = 0; t < 4; ++t)
#pragma unroll
      for (int q = 0; q < 4; ++q) {
        float v = macc[t][q];
        v += __shfl_xor(v, 1);
        v += __shfl_xor(v, 2);
        v += __shfl_xor(v, 4);
        v += __shfl_xor(v, 8);
        macc[t][q] = v;
      }
    if (l15 == 0) {
      float fc = (float)cnt;
      float* mr = msg + (size_t)n * MSG;
#pragma unroll
      for (int t = 0; t < 4; ++t) {
        v4f o;
#pragma unroll
        for (int q = 0; q < 4; ++q)
          o[q] = macc[t][q] + fc * mb3[t * 16 + 4 * lq + q];
        *reinterpret_cast<v4f*>(mr + t * 16 + 4 * lq) = o;
      }
    }
  }
}

// ---------------- node update: same structure, 16 nodes per wave ----------------
// msg aliases out (d_out): every store is data-dependent on ALL of the wave's
// msg loads (through the MFMA chain), so reads complete before writes.
__global__ __launch_bounds__(256, 1) void node_mfma_kernel(
    const float* __restrict__ x, const float* msg,
    const float* __restrict__ oW1, const float* __restrict__ ob1,
    const float* __restrict__ oW2, const float* __restrict__ ob2,
    const float* __restrict__ oW3, const float* __restrict__ ob3,
    float* out) {
  const int l15 = threadIdx.x & 15;
  const int lq = (threadIdx.x & 63) >> 4;
  const int tile = (blockIdx.x * 256 + threadIdx.x) >> 6;
  if (tile >= NP / 16) return;   // NP % 16 == 0

  v8s w1h[2][4], w1l[2][4], w2h[2], w2l[2], w3h[4], w3l[4];
#pragma unroll
  for (int t = 0; t < 2; ++t)
#pragma unroll
    for (int kc = 0; kc < 4; ++kc)
      load_wfrag(oW1, HID, kc * 32, t * 16, lq, l15, &w1h[t][kc], &w1l[t][kc]);
#pragma unroll
  for (int t = 0; t < 2; ++t)
    load_wfrag(oW2, HID, 0, t * 16, lq, l15, &w2h[t], &w2l[t]);
#pragma unroll
  for (int t = 0; t < 4; ++t)
    load_wfrag(oW3, SD, 0, t * 16, lq, l15, &w3h[t], &w3l[t]);

  const int node = tile * 16 + l15;
  const float* xn = x + (size_t)node * SD;
  const float* mn = msg + (size_t)node * MSG;

  v4f d0 = *reinterpret_cast<const v4f*>(ob1 + 4 * lq);
  v4f d1 = *reinterpret_cast<const v4f*>(ob1 + 16 + 4 * lq);
#pragma unroll
  for (int kc = 0; kc < 2; ++kc) {
    v8s xh, xl;
    load_xfrag(xn, kc * 32, lq, &xh, &xl);
    d0 = mfma3(w1h[0][kc], w1l[0][kc], xh, xl, d0);
    d1 = mfma3(w1h[1][kc], w1l[1][kc], xh, xl, d1);
  }
#pragma unroll
  for (int kc = 0; kc < 2; ++kc) {
    v8s xh, xl;
    load_xfrag(mn, kc * 32, lq, &xh, &xl);
    d0 = mfma3(w1h[0][2 + kc], w1l[0][2 + kc], xh, xl, d0);
    d1 = mfma3(w1h[1][2 + kc], w1l[1][2 + kc], xh, xl, d1);
  }

  v8s ph, pl;
  chain_frag(d0, d1, &ph, &pl);
  v4f e0 = *reinterpret_cast<const v4f*>(ob2 + 4 * lq);
  v4f e1 = *reinterpret_cast<const v4f*>(ob2 + 16 + 4 * lq);
  e0 = mfma3(w2h[0], w2l[0], ph, pl, e0);
  e1 = mfma3(w2h[1], w2l[1], ph, pl, e1);

  v8s rh, rl;
  chain_frag(e0, e1, &rh, &rl);

  float* orow = out + (size_t)node * SD;
#pragma unroll
  for (int t = 0; t < 4; ++t) {
    v4f c = *reinterpret_cast<const v4f*>(ob3 + t * 16 + 4 * lq);
    c = mfma3(w3h[t], w3l[t], rh, rl, c);
    *reinterpret_cast<v4f*>(orow + t * 16 + 4 * lq) = c;
  }
}

extern "C" void kernel_launch(void* const* d_in, const int* in_sizes, int n_in,
                              void* d_out, int out_size, void* d_ws,
                              size_t ws_size, hipStream_t stream) {
  const float* x = (const float*)d_in[0];
  const int* ei = (const int*)d_in[1];
  const float* mW1 = (const float*)d_in[2];
  const float* mb1 = (const float*)d_in[3];
  const float* mW2 = (const float*)d_in[4];
  const float* mb2 = (const float*)d_in[5];
  const float* mW3 = (const float*)d_in[6];
  const float* mb3 = (const float*)d_in[7];
  const float* oW1 = (const float*)d_in[8];
  const float* ob1 = (const float*)d_in[9];
  const float* oW2 = (const float*)d_in[10];
  const float* ob2 = (const float*)d_in[11];
  const float* oW3 = (const float*)d_in[12];
  const float* ob3 = (const float*)d_in[13];
  float* out = (float*)d_out;

  // ws (ints): counts | offsets | cursor | bsums(512) | csr_src  (~7.6 MB)
  int* counts = (int*)d_ws;
  int* offsets = counts + NP_PAD;
  int* cursor = offsets + NP_PAD;
  int* bsums = cursor + NP_PAD;
  int* csr_src = bsums + 512;

  float* msg = out;   // msg aliases d_out (RAW-safe, see node kernel comment)

  hipMemsetAsync(counts, 0, NP_PAD * sizeof(int), stream);

  hist_kernel<<<(NE + 255) / 256, 256, 0, stream>>>(ei, counts);
  scan1_kernel<<<NBLK, SCAN_B, 0, stream>>>(counts, offsets, bsums);
  scan2_kernel<<<1, 512, 0, stream>>>(bsums);
  scan3_kernel<<<NBLK, SCAN_B, 0, stream>>>(offsets, bsums, cursor);
  scatter_kernel<<<(NE + 255) / 256, 256, 0, stream>>>(ei, cursor, csr_src);

  edge_mfma_kernel<<<2048, 256, 0, stream>>>(
      x, counts, offsets, csr_src, mW1, mb1, mW2, mb2, mW3, mb3, msg);

  node_mfma_kernel<<<(NP / 16 + 3) / 4, 256, 0, stream>>>(
      x, msg, oW1, ob1, oW2, ob2, oW3, ob3, out);
}

// Round 6
// 592.603 us; speedup vs baseline: 9.4490x; 1.0320x over previous
//
#include <hip/hip_runtime.h>

#define NP 100000
#define NE 1600000
#define SD 64      // STATE_DIM
#define HID 32
#define MSG 64
#define NP_PAD 100352
#define SCAN_B 256
#define NBLK ((NP + SCAN_B - 1) / SCAN_B)   // 391

typedef float v4f __attribute__((ext_vector_type(4)));
typedef short v4s __attribute__((ext_vector_type(4)));
typedef short v8s __attribute__((ext_vector_type(8)));
typedef __bf16 v8bf __attribute__((ext_vector_type(8)));

// weight-frag ids in the prequant buffer (each = 64 lanes x v8s):
// 0-3 w1s hi [t*2+kc], 4-7 w1s lo, 8-11 w1d hi, 12-15 w1d lo,
// 16-17 w2 hi[t], 18-19 w2 lo, 20-23 w3 hi[t], 24-27 w3 lo
#define WQ_FRAGS 28

__device__ __forceinline__ v4f MFMA32(v8s a, v8s b, v4f c) {
  return __builtin_amdgcn_mfma_f32_16x16x32_bf16(
      __builtin_bit_cast(v8bf, a), __builtin_bit_cast(v8bf, b), c, 0, 0, 0);
}

__device__ __forceinline__ short f2bf(float f) {
  unsigned u = __builtin_bit_cast(unsigned, f);
  u += 0x7FFFu + ((u >> 16) & 1u);   // RNE
  return (short)(u >> 16);
}
__device__ __forceinline__ float bf2f(short s) {
  unsigned u = ((unsigned)(unsigned short)s) << 16;
  return __builtin_bit_cast(float, u);
}

// 3-term split-bf16 product: C += Ah*Bh + Ah*Bl + Al*Bh (error ~2^-17 rel)
__device__ __forceinline__ v4f mfma3(v8s ah, v8s al, v8s bh, v8s bl, v4f c) {
  c = MFMA32(al, bh, c);
  c = MFMA32(ah, bl, c);
  c = MFMA32(ah, bh, c);
  return c;
}

// A-frag (hi/lo) from row-major W[K][ld]: A[m][k] = W[k][m0+l15]
__device__ __forceinline__ void load_wfrag(const float* __restrict__ W, int ld,
                                           int kb, int m0, int lq, int l15,
                                           v8s* hi, v8s* lo) {
  v8s h, l;
#pragma unroll
  for (int j = 0; j < 8; ++j) {
    int k = kb + ((j < 4) ? (4 * lq + j) : (16 + 4 * lq + (j - 4)));
    float v = W[k * ld + m0 + l15];
    short hb = f2bf(v);
    h[j] = hb;
    l[j] = f2bf(v - bf2f(hb));
  }
  *hi = h;
  *lo = l;
}

// B-frag (hi/lo) from an f32 feature row (fallback path)
__device__ __forceinline__ void load_xfrag(const float* xs, int kb, int lq,
                                           v8s* hi, v8s* lo) {
  v4f a = *reinterpret_cast<const v4f*>(xs + kb + 4 * lq);
  v4f b = *reinterpret_cast<const v4f*>(xs + kb + 16 + 4 * lq);
  v8s h, l;
#pragma unroll
  for (int j = 0; j < 4; ++j) {
    short ha = f2bf(a[j]); h[j] = ha; l[j] = f2bf(a[j] - bf2f(ha));
    short hb = f2bf(b[j]); h[j + 4] = hb; l[j + 4] = f2bf(b[j] - bf2f(hb));
  }
  *hi = h;
  *lo = l;
}

// B-frag from a prequantized short row: two dwordx2 loads, zero VALU
__device__ __forceinline__ v8s ldfrag(const short* row, int kb, int lq) {
  v4s a = *reinterpret_cast<const v4s*>(row + kb + 4 * lq);
  v4s b = *reinterpret_cast<const v4s*>(row + kb + 16 + 4 * lq);
  return __builtin_shufflevector(a, b, 0, 1, 2, 3, 4, 5, 6, 7);
}

// layer1->layer2 chaining: D blocks -> next B-frag with relu, split hi/lo
__device__ __forceinline__ void chain_frag(v4f d0, v4f d1, v8s* hi, v8s* lo) {
  v8s h, l;
#pragma unroll
  for (int j = 0; j < 4; ++j) {
    float v0 = fmaxf(d0[j], 0.f);
    float v1 = fmaxf(d1[j], 0.f);
    short h0 = f2bf(v0); h[j] = h0;     l[j] = f2bf(v0 - bf2f(h0));
    short h1 = f2bf(v1); h[j + 4] = h1; l[j + 4] = f2bf(v1 - bf2f(h1));
  }
  *hi = h;
  *lo = l;
}

// ---------------- prequantization ----------------

__global__ void preq_kernel(const float* __restrict__ x, short* __restrict__ xh,
                            short* __restrict__ xl) {
  int i = blockIdx.x * 256 + threadIdx.x;   // one thread per 4 values
  if (i >= NP * SD / 4) return;
  v4f v = reinterpret_cast<const v4f*>(x)[i];
  v4s h, l;
#pragma unroll
  for (int j = 0; j < 4; ++j) {
    short hb = f2bf(v[j]);
    h[j] = hb;
    l[j] = f2bf(v[j] - bf2f(hb));
  }
  reinterpret_cast<v4s*>(xh)[i] = h;
  reinterpret_cast<v4s*>(xl)[i] = l;
}

__global__ void prew_kernel(const float* __restrict__ mW1,
                            const float* __restrict__ mW2,
                            const float* __restrict__ mW3,
                            short* __restrict__ wqs) {
  int lane = threadIdx.x;   // 64 threads, 1 block
  int l15 = lane & 15, lq = lane >> 4;
  v8s* wq = reinterpret_cast<v8s*>(wqs);
  v8s h, l;
#pragma unroll
  for (int t = 0; t < 2; ++t)
#pragma unroll
    for (int kc = 0; kc < 2; ++kc) {
      load_wfrag(mW1, HID, kc * 32, t * 16, lq, l15, &h, &l);
      wq[(t * 2 + kc) * 64 + lane] = h;
      wq[(4 + t * 2 + kc) * 64 + lane] = l;
      load_wfrag(mW1, HID, 64 + kc * 32, t * 16, lq, l15, &h, &l);
      wq[(8 + t * 2 + kc) * 64 + lane] = h;
      wq[(12 + t * 2 + kc) * 64 + lane] = l;
    }
#pragma unroll
  for (int t = 0; t < 2; ++t) {
    load_wfrag(mW2, HID, 0, t * 16, lq, l15, &h, &l);
    wq[(16 + t) * 64 + lane] = h;
    wq[(18 + t) * 64 + lane] = l;
  }
#pragma unroll
  for (int t = 0; t < 4; ++t) {
    load_wfrag(mW3, MSG, 0, t * 16, lq, l15, &h, &l);
    wq[(20 + t) * 64 + lane] = h;
    wq[(24 + t) * 64 + lane] = l;
  }
}

// ---------------- CSR build (proven) ----------------

__global__ void hist_kernel(const int* __restrict__ ei, int* __restrict__ counts) {
  int e = blockIdx.x * 256 + threadIdx.x;
  if (e >= NE) return;
  atomicAdd(&counts[ei[NE + e]], 1);
}

__global__ void scan1_kernel(const int* __restrict__ counts,
                             int* __restrict__ offsets, int* __restrict__ bsums) {
  __shared__ int s[SCAN_B];
  int t = threadIdx.x;
  int i = blockIdx.x * SCAN_B + t;
  int v = (i < NP) ? counts[i] : 0;
  s[t] = v;
  __syncthreads();
  for (int off = 1; off < SCAN_B; off <<= 1) {
    int a = (t >= off) ? s[t - off] : 0;
    __syncthreads();
    s[t] += a;
    __syncthreads();
  }
  if (i < NP) offsets[i] = s[t] - v;
  if (t == SCAN_B - 1) bsums[blockIdx.x] = s[t];
}

__global__ void scan2_kernel(int* __restrict__ bsums) {
  __shared__ int s[512];
  int t = threadIdx.x;
  int v = (t < NBLK) ? bsums[t] : 0;
  s[t] = v;
  __syncthreads();
  for (int off = 1; off < 512; off <<= 1) {
    int a = (t >= off) ? s[t - off] : 0;
    __syncthreads();
    s[t] += a;
    __syncthreads();
  }
  if (t < NBLK) bsums[t] = s[t] - v;
}

__global__ void scan3_kernel(int* __restrict__ offsets,
                             const int* __restrict__ bsums,
                             int* __restrict__ cursor) {
  int i = blockIdx.x * SCAN_B + threadIdx.x;
  if (i >= NP) return;
  int o = offsets[i] + bsums[blockIdx.x];
  offsets[i] = o;
  cursor[i] = o;
}

__global__ void scatter_kernel(const int* __restrict__ ei,
                               int* __restrict__ cursor, int* __restrict__ csr_src) {
  int e = blockIdx.x * 256 + threadIdx.x;
  if (e >= NE) return;
  int src = ei[e];
  int dst = ei[NE + e];
  int pos = atomicAdd(&cursor[dst], 1);
  csr_src[pos] = src;
}

// ---------------- edge messages ----------------
// Per node: h1d (dst-half, once) -> per 16-edge group: layer1+layer2 MFMA,
// relu(e) accumulated per-lane in f32; layer3 deferred to once per node
// (linear => sum commutes). Layer-3 + w1-dst frags loaded per-node (scoped).
template <bool PREQ>
__global__ __launch_bounds__(256, 4) void edge_mfma_kernel(
    const float* __restrict__ x, const short* __restrict__ xh,
    const short* __restrict__ xl, const short* __restrict__ wqs,
    const int* __restrict__ counts, const int* __restrict__ offsets,
    const int* __restrict__ csr_src,
    const float* __restrict__ mW1, const float* __restrict__ mb1,
    const float* __restrict__ mW2, const float* __restrict__ mb2,
    const float* __restrict__ mW3, const float* __restrict__ mb3,
    float* __restrict__ msg) {
  const int lane = threadIdx.x & 63;
  const int l15 = lane & 15;
  const int lq = lane >> 4;
  const int wid = (blockIdx.x * 256 + threadIdx.x) >> 6;
  const int nw = gridDim.x * 4;
  const v8s* wq = reinterpret_cast<const v8s*>(wqs);

  // resident weights: layer1-src + layer2 only (48 VGPR)
  v8s w1sh[2][2], w1sl[2][2], w2h[2], w2l[2];
#pragma unroll
  for (int t = 0; t < 2; ++t)
#pragma unroll
    for (int kc = 0; kc < 2; ++kc) {
      if constexpr (PREQ) {
        w1sh[t][kc] = wq[(t * 2 + kc) * 64 + lane];
        w1sl[t][kc] = wq[(4 + t * 2 + kc) * 64 + lane];
      } else {
        load_wfrag(mW1, HID, kc * 32, t * 16, lq, l15, &w1sh[t][kc], &w1sl[t][kc]);
      }
    }
#pragma unroll
  for (int t = 0; t < 2; ++t) {
    if constexpr (PREQ) {
      w2h[t] = wq[(16 + t) * 64 + lane];
      w2l[t] = wq[(18 + t) * 64 + lane];
    } else {
      load_wfrag(mW2, HID, 0, t * 16, lq, l15, &w2h[t], &w2l[t]);
    }
  }

  for (int n = wid; n < NP; n += nw) {
    const int cnt = counts[n];
    const int off = offsets[n];
    const int ng = (cnt + 15) >> 4;

    // dst-half of layer1 + bias, once per node (w1d frags scoped here)
    v4f h1d0 = *reinterpret_cast<const v4f*>(mb1 + 4 * lq);
    v4f h1d1 = *reinterpret_cast<const v4f*>(mb1 + 16 + 4 * lq);
#pragma unroll
    for (int kc = 0; kc < 2; ++kc) {
      v8s xhf, xlf;
      if constexpr (PREQ) {
        xhf = ldfrag(xh + (size_t)n * SD, kc * 32, lq);
        xlf = ldfrag(xl + (size_t)n * SD, kc * 32, lq);
      } else {
        load_xfrag(x + (size_t)n * SD, kc * 32, lq, &xhf, &xlf);
      }
#pragma unroll
      for (int t = 0; t < 2; ++t) {
        v8s dh, dl;
        if constexpr (PREQ) {
          dh = wq[(8 + t * 2 + kc) * 64 + lane];
          dl = wq[(12 + t * 2 + kc) * 64 + lane];
        } else {
          load_wfrag(mW1, HID, 64 + kc * 32, t * 16, lq, l15, &dh, &dl);
        }
        if (t == 0) h1d0 = mfma3(dh, dl, xhf, xlf, h1d0);
        else        h1d1 = mfma3(dh, dl, xhf, xlf, h1d1);
      }
    }

    v4f r0 = {0.f, 0.f, 0.f, 0.f}, r1 = {0.f, 0.f, 0.f, 0.f};

    int rem = cnt;
    bool vcur = l15 < rem;
    int s = vcur ? csr_src[off + l15] : n;
    for (int g = 0; g < ng; ++g) {
      // gather current group's src fragments
      v8s xh0, xl0, xh1, xl1;
      if constexpr (PREQ) {
        const short* rh = xh + (size_t)s * SD;
        const short* rl = xl + (size_t)s * SD;
        xh0 = ldfrag(rh, 0, lq);
        xl0 = ldfrag(rl, 0, lq);
        xh1 = ldfrag(rh, 32, lq);
        xl1 = ldfrag(rl, 32, lq);
      } else {
        const float* xs = x + (size_t)s * SD;
        load_xfrag(xs, 0, lq, &xh0, &xl0);
        load_xfrag(xs, 32, lq, &xh1, &xl1);
      }
      // prefetch next group's src index (hides csr load latency)
      int rem2 = rem - 16;
      bool vnxt = l15 < rem2;
      int s2 = vnxt ? csr_src[off + (g + 1) * 16 + l15] : n;

      v4f d0 = h1d0, d1 = h1d1;
      d0 = mfma3(w1sh[0][0], w1sl[0][0], xh0, xl0, d0);
      d0 = mfma3(w1sh[0][1], w1sl[0][1], xh1, xl1, d0);
      d1 = mfma3(w1sh[1][0], w1sl[1][0], xh0, xl0, d1);
      d1 = mfma3(w1sh[1][1], w1sl[1][1], xh1, xl1, d1);

      v8s ph, pl;
      chain_frag(d0, d1, &ph, &pl);
      v4f e0 = *reinterpret_cast<const v4f*>(mb2 + 4 * lq);
      v4f e1 = *reinterpret_cast<const v4f*>(mb2 + 16 + 4 * lq);
      e0 = mfma3(w2h[0], w2l[0], ph, pl, e0);
      e1 = mfma3(w2h[1], w2l[1], ph, pl, e1);

      if (vcur) {
#pragma unroll
        for (int j = 0; j < 4; ++j) {
          r0[j] += fmaxf(e0[j], 0.f);
          r1[j] += fmaxf(e1[j], 0.f);
        }
      }
      vcur = vnxt;
      s = s2;
      rem = rem2;
    }

    // reduce relu-sums over the 16 slot-columns (xor broadcast to all lanes)
#pragma unroll
    for (int j = 0; j < 4; ++j) {
      float a = r0[j], b = r1[j];
      a += __shfl_xor(a, 1); a += __shfl_xor(a, 2);
      a += __shfl_xor(a, 4); a += __shfl_xor(a, 8);
      b += __shfl_xor(b, 1); b += __shfl_xor(b, 2);
      b += __shfl_xor(b, 4); b += __shfl_xor(b, 8);
      r0[j] = a; r1[j] = b;
    }
    // quantize summed r once -> single-column B-frag (uniform across cols)
    v8s bh, bl;
#pragma unroll
    for (int j = 0; j < 4; ++j) {
      short h0 = f2bf(r0[j]); bh[j] = h0;     bl[j] = f2bf(r0[j] - bf2f(h0));
      short h1 = f2bf(r1[j]); bh[j + 4] = h1; bl[j + 4] = f2bf(r1[j] - bf2f(h1));
    }
    float fc = (float)cnt;
#pragma unroll
    for (int t = 0; t < 4; ++t) {
      v8s ah, al;
      if constexpr (PREQ) {
        ah = wq[(20 + t) * 64 + lane];
        al = wq[(24 + t) * 64 + lane];
      } else {
        load_wfrag(mW3, MSG, 0, t * 16, lq, l15, &ah, &al);
      }
      v4f c = {0.f, 0.f, 0.f, 0.f};
      c = mfma3(ah, al, bh, bl, c);
      if (l15 == 0) {
        v4f o;
#pragma unroll
        for (int q = 0; q < 4; ++q)
          o[q] = c[q] + fc * mb3[t * 16 + 4 * lq + q];
        *reinterpret_cast<v4f*>(msg + (size_t)n * MSG + t * 16 + 4 * lq) = o;
      }
    }
  }
}

// ---------------- node update (R5-proven, 16 nodes/wave) ----------------
// msg aliases out: every store data-depends on all of the wave's msg reads.
__global__ __launch_bounds__(256, 1) void node_mfma_kernel(
    const float* __restrict__ x, const float* msg,
    const float* __restrict__ oW1, const float* __restrict__ ob1,
    const float* __restrict__ oW2, const float* __restrict__ ob2,
    const float* __restrict__ oW3, const float* __restrict__ ob3,
    float* out) {
  const int l15 = threadIdx.x & 15;
  const int lq = (threadIdx.x & 63) >> 4;
  const int tile = (blockIdx.x * 256 + threadIdx.x) >> 6;
  if (tile >= NP / 16) return;   // NP % 16 == 0

  v8s w1h[2][4], w1l[2][4], w2h[2], w2l[2], w3h[4], w3l[4];
#pragma unroll
  for (int t = 0; t < 2; ++t)
#pragma unroll
    for (int kc = 0; kc < 4; ++kc)
      load_wfrag(oW1, HID, kc * 32, t * 16, lq, l15, &w1h[t][kc], &w1l[t][kc]);
#pragma unroll
  for (int t = 0; t < 2; ++t)
    load_wfrag(oW2, HID, 0, t * 16, lq, l15, &w2h[t], &w2l[t]);
#pragma unroll
  for (int t = 0; t < 4; ++t)
    load_wfrag(oW3, SD, 0, t * 16, lq, l15, &w3h[t], &w3l[t]);

  const int node = tile * 16 + l15;
  const float* xn = x + (size_t)node * SD;
  const float* mn = msg + (size_t)node * MSG;

  v4f d0 = *reinterpret_cast<const v4f*>(ob1 + 4 * lq);
  v4f d1 = *reinterpret_cast<const v4f*>(ob1 + 16 + 4 * lq);
#pragma unroll
  for (int kc = 0; kc < 2; ++kc) {
    v8s xhf, xlf;
    load_xfrag(xn, kc * 32, lq, &xhf, &xlf);
    d0 = mfma3(w1h[0][kc], w1l[0][kc], xhf, xlf, d0);
    d1 = mfma3(w1h[1][kc], w1l[1][kc], xhf, xlf, d1);
  }
#pragma unroll
  for (int kc = 0; kc < 2; ++kc) {
    v8s xhf, xlf;
    load_xfrag(mn, kc * 32, lq, &xhf, &xlf);
    d0 = mfma3(w1h[0][2 + kc], w1l[0][2 + kc], xhf, xlf, d0);
    d1 = mfma3(w1h[1][2 + kc], w1l[1][2 + kc], xhf, xlf, d1);
  }

  v8s ph, pl;
  chain_frag(d0, d1, &ph, &pl);
  v4f e0 = *reinterpret_cast<const v4f*>(ob2 + 4 * lq);
  v4f e1 = *reinterpret_cast<const v4f*>(ob2 + 16 + 4 * lq);
  e0 = mfma3(w2h[0], w2l[0], ph, pl, e0);
  e1 = mfma3(w2h[1], w2l[1], ph, pl, e1);

  v8s rh, rl;
  chain_frag(e0, e1, &rh, &rl);

  float* orow = out + (size_t)node * SD;
#pragma unroll
  for (int t = 0; t < 4; ++t) {
    v4f c = *reinterpret_cast<const v4f*>(ob3 + t * 16 + 4 * lq);
    c = mfma3(w3h[t], w3l[t], rh, rl, c);
    *reinterpret_cast<v4f*>(orow + t * 16 + 4 * lq) = c;
  }
}

extern "C" void kernel_launch(void* const* d_in, const int* in_sizes, int n_in,
                              void* d_out, int out_size, void* d_ws,
                              size_t ws_size, hipStream_t stream) {
  const float* x = (const float*)d_in[0];
  const int* ei = (const int*)d_in[1];
  const float* mW1 = (const float*)d_in[2];
  const float* mb1 = (const float*)d_in[3];
  const float* mW2 = (const float*)d_in[4];
  const float* mb2 = (const float*)d_in[5];
  const float* mW3 = (const float*)d_in[6];
  const float* mb3 = (const float*)d_in[7];
  const float* oW1 = (const float*)d_in[8];
  const float* ob1 = (const float*)d_in[9];
  const float* oW2 = (const float*)d_in[10];
  const float* ob2 = (const float*)d_in[11];
  const float* oW3 = (const float*)d_in[12];
  const float* ob3 = (const float*)d_in[13];
  float* out = (float*)d_out;

  const size_t xq_elems = (size_t)NP * SD;                 // shorts per array
  const size_t wq_bytes = (size_t)WQ_FRAGS * 64 * 16;      // 28 KiB
  const size_t int_bytes = ((size_t)3 * NP_PAD + 512 + NE) * 4;
  const size_t preq_bytes = 2 * xq_elems * 2 + wq_bytes + int_bytes;
  const bool preq = ws_size >= preq_bytes;

  short* xh = nullptr;
  short* xl = nullptr;
  short* wqs = nullptr;
  int* ints;
  if (preq) {
    xh = (short*)d_ws;
    xl = xh + xq_elems;
    wqs = xl + xq_elems;
    ints = (int*)((char*)wqs + wq_bytes);
  } else {
    ints = (int*)d_ws;
  }
  int* counts = ints;
  int* offsets = counts + NP_PAD;
  int* cursor = offsets + NP_PAD;
  int* bsums = cursor + NP_PAD;
  int* csr_src = bsums + 512;

  float* msg = out;   // msg aliases d_out (RAW-safe in node kernel)

  hipMemsetAsync(counts, 0, NP_PAD * sizeof(int), stream);

  if (preq) {
    preq_kernel<<<(NP * SD / 4 + 255) / 256, 256, 0, stream>>>(x, xh, xl);
    prew_kernel<<<1, 64, 0, stream>>>(mW1, mW2, mW3, wqs);
  }

  hist_kernel<<<(NE + 255) / 256, 256, 0, stream>>>(ei, counts);
  scan1_kernel<<<NBLK, SCAN_B, 0, stream>>>(counts, offsets, bsums);
  scan2_kernel<<<1, 512, 0, stream>>>(bsums);
  scan3_kernel<<<NBLK, SCAN_B, 0, stream>>>(offsets, bsums, cursor);
  scatter_kernel<<<(NE + 255) / 256, 256, 0, stream>>>(ei, cursor, csr_src);

  if (preq) {
    edge_mfma_kernel<true><<<2048, 256, 0, stream>>>(
        x, xh, xl, wqs, counts, offsets, csr_src,
        mW1, mb1, mW2, mb2, mW3, mb3, msg);
  } else {
    edge_mfma_kernel<false><<<2048, 256, 0, stream>>>(
        x, xh, xl, wqs, counts, offsets, csr_src,
        mW1, mb1, mW2, mb2, mW3, mb3, msg);
  }

  node_mfma_kernel<<<(NP / 16 + 3) / 4, 256, 0, stream>>>(
      x, msg, oW1, ob1, oW2, ob2, oW3, ob3, out);
}

// Round 7
// 500.887 us; speedup vs baseline: 11.1791x; 1.1831x over previous
//
#include <hip/hip_runtime.h>

#define NP 100000
#define NE 1600000
#define SD 64      // STATE_DIM
#define HID 32
#define MSG 64
#define NP_PAD 100352
#define SCAN_B 256
#define NBLK ((NP + SCAN_B - 1) / SCAN_B)   // 391

typedef float v4f __attribute__((ext_vector_type(4)));
typedef short v4s __attribute__((ext_vector_type(4)));
typedef short v8s __attribute__((ext_vector_type(8)));
typedef __bf16 v8bf __attribute__((ext_vector_type(8)));

// weight-frag ids in the prequant buffer (each frag = 64 lanes x v8s = 1 KiB):
// edge MLP: 0-3 w1s hi [t*2+kc], 4-7 w1s lo, 8-11 w1d hi, 12-15 w1d lo,
//           16-17 w2 hi[t], 18-19 w2 lo, 20-23 w3 hi[t], 24-27 w3 lo
// node MLP: 28-35 oW1 hi [t*4+kc], 36-43 oW1 lo, 44-45 oW2 hi, 46-47 oW2 lo,
//           48-51 oW3 hi[t], 52-55 oW3 lo
#define WQ_FRAGS 56

__device__ __forceinline__ v4f MFMA32(v8s a, v8s b, v4f c) {
  return __builtin_amdgcn_mfma_f32_16x16x32_bf16(
      __builtin_bit_cast(v8bf, a), __builtin_bit_cast(v8bf, b), c, 0, 0, 0);
}

__device__ __forceinline__ short f2bf(float f) {
  unsigned u = __builtin_bit_cast(unsigned, f);
  u += 0x7FFFu + ((u >> 16) & 1u);   // RNE
  return (short)(u >> 16);
}
__device__ __forceinline__ float bf2f(short s) {
  unsigned u = ((unsigned)(unsigned short)s) << 16;
  return __builtin_bit_cast(float, u);
}

// 3-term split-bf16 product: C += Ah*Bh + Ah*Bl + Al*Bh (error ~2^-17 rel)
__device__ __forceinline__ v4f mfma3(v8s ah, v8s al, v8s bh, v8s bl, v4f c) {
  c = MFMA32(al, bh, c);
  c = MFMA32(ah, bl, c);
  c = MFMA32(ah, bh, c);
  return c;
}

// A-frag (hi/lo) from row-major W[K][ld]: A[m][k] = W[k][m0+l15]
__device__ __forceinline__ void load_wfrag(const float* __restrict__ W, int ld,
                                           int kb, int m0, int lq, int l15,
                                           v8s* hi, v8s* lo) {
  v8s h, l;
#pragma unroll
  for (int j = 0; j < 8; ++j) {
    int k = kb + ((j < 4) ? (4 * lq + j) : (16 + 4 * lq + (j - 4)));
    float v = W[k * ld + m0 + l15];
    short hb = f2bf(v);
    h[j] = hb;
    l[j] = f2bf(v - bf2f(hb));
  }
  *hi = h;
  *lo = l;
}

// B-frag (hi/lo) from an f32 feature row (fallback path)
__device__ __forceinline__ void load_xfrag(const float* xs, int kb, int lq,
                                           v8s* hi, v8s* lo) {
  v4f a = *reinterpret_cast<const v4f*>(xs + kb + 4 * lq);
  v4f b = *reinterpret_cast<const v4f*>(xs + kb + 16 + 4 * lq);
  v8s h, l;
#pragma unroll
  for (int j = 0; j < 4; ++j) {
    short ha = f2bf(a[j]); h[j] = ha; l[j] = f2bf(a[j] - bf2f(ha));
    short hb = f2bf(b[j]); h[j + 4] = hb; l[j + 4] = f2bf(b[j] - bf2f(hb));
  }
  *hi = h;
  *lo = l;
}

// hi-only B-frag from an f32 feature row (fallback src gather)
__device__ __forceinline__ v8s load_xfrag_hi(const float* xs, int kb, int lq) {
  v4f a = *reinterpret_cast<const v4f*>(xs + kb + 4 * lq);
  v4f b = *reinterpret_cast<const v4f*>(xs + kb + 16 + 4 * lq);
  v8s h;
#pragma unroll
  for (int j = 0; j < 4; ++j) {
    h[j] = f2bf(a[j]);
    h[j + 4] = f2bf(b[j]);
  }
  return h;
}

// B-frag from a prequantized short row: two dwordx2 loads, zero VALU
__device__ __forceinline__ v8s ldfrag(const short* row, int kb, int lq) {
  v4s a = *reinterpret_cast<const v4s*>(row + kb + 4 * lq);
  v4s b = *reinterpret_cast<const v4s*>(row + kb + 16 + 4 * lq);
  return __builtin_shufflevector(a, b, 0, 1, 2, 3, 4, 5, 6, 7);
}

// layer->layer chaining: D blocks -> next B-frag with relu, split hi/lo
__device__ __forceinline__ void chain_frag(v4f d0, v4f d1, v8s* hi, v8s* lo) {
  v8s h, l;
#pragma unroll
  for (int j = 0; j < 4; ++j) {
    float v0 = fmaxf(d0[j], 0.f);
    float v1 = fmaxf(d1[j], 0.f);
    short h0 = f2bf(v0); h[j] = h0;     l[j] = f2bf(v0 - bf2f(h0));
    short h1 = f2bf(v1); h[j + 4] = h1; l[j + 4] = f2bf(v1 - bf2f(h1));
  }
  *hi = h;
  *lo = l;
}

// ---------------- prequantization ----------------

__global__ void preq_kernel(const float* __restrict__ x, short* __restrict__ xh,
                            short* __restrict__ xl) {
  int i = blockIdx.x * 256 + threadIdx.x;   // one thread per 4 values
  if (i >= NP * SD / 4) return;
  v4f v = reinterpret_cast<const v4f*>(x)[i];
  v4s h, l;
#pragma unroll
  for (int j = 0; j < 4; ++j) {
    short hb = f2bf(v[j]);
    h[j] = hb;
    l[j] = f2bf(v[j] - bf2f(hb));
  }
  reinterpret_cast<v4s*>(xh)[i] = h;
  reinterpret_cast<v4s*>(xl)[i] = l;
}

__global__ void prew_kernel(const float* __restrict__ mW1,
                            const float* __restrict__ mW2,
                            const float* __restrict__ mW3,
                            const float* __restrict__ oW1,
                            const float* __restrict__ oW2,
                            const float* __restrict__ oW3,
                            short* __restrict__ wqs) {
  int lane = threadIdx.x;   // 64 threads, 1 block
  int l15 = lane & 15, lq = lane >> 4;
  v8s* wq = reinterpret_cast<v8s*>(wqs);
  v8s h, l;
#pragma unroll
  for (int t = 0; t < 2; ++t)
#pragma unroll
    for (int kc = 0; kc < 2; ++kc) {
      load_wfrag(mW1, HID, kc * 32, t * 16, lq, l15, &h, &l);
      wq[(t * 2 + kc) * 64 + lane] = h;
      wq[(4 + t * 2 + kc) * 64 + lane] = l;
      load_wfrag(mW1, HID, 64 + kc * 32, t * 16, lq, l15, &h, &l);
      wq[(8 + t * 2 + kc) * 64 + lane] = h;
      wq[(12 + t * 2 + kc) * 64 + lane] = l;
    }
#pragma unroll
  for (int t = 0; t < 2; ++t) {
    load_wfrag(mW2, HID, 0, t * 16, lq, l15, &h, &l);
    wq[(16 + t) * 64 + lane] = h;
    wq[(18 + t) * 64 + lane] = l;
  }
#pragma unroll
  for (int t = 0; t < 4; ++t) {
    load_wfrag(mW3, MSG, 0, t * 16, lq, l15, &h, &l);
    wq[(20 + t) * 64 + lane] = h;
    wq[(24 + t) * 64 + lane] = l;
  }
  // node MLP weights
#pragma unroll
  for (int t = 0; t < 2; ++t)
#pragma unroll
    for (int kc = 0; kc < 4; ++kc) {
      load_wfrag(oW1, HID, kc * 32, t * 16, lq, l15, &h, &l);
      wq[(28 + t * 4 + kc) * 64 + lane] = h;
      wq[(36 + t * 4 + kc) * 64 + lane] = l;
    }
#pragma unroll
  for (int t = 0; t < 2; ++t) {
    load_wfrag(oW2, HID, 0, t * 16, lq, l15, &h, &l);
    wq[(44 + t) * 64 + lane] = h;
    wq[(46 + t) * 64 + lane] = l;
  }
#pragma unroll
  for (int t = 0; t < 4; ++t) {
    load_wfrag(oW3, SD, 0, t * 16, lq, l15, &h, &l);
    wq[(48 + t) * 64 + lane] = h;
    wq[(52 + t) * 64 + lane] = l;
  }
}

// ---------------- CSR build ----------------

__global__ void hist_kernel(const int* __restrict__ ei, int* __restrict__ counts) {
  int i = blockIdx.x * 256 + threadIdx.x;   // 4 edges per thread
  if (i >= NE / 4) return;
  int4 d = reinterpret_cast<const int4*>(ei + NE)[i];
  atomicAdd(&counts[d.x], 1);
  atomicAdd(&counts[d.y], 1);
  atomicAdd(&counts[d.z], 1);
  atomicAdd(&counts[d.w], 1);
}

__global__ void scan1_kernel(const int* __restrict__ counts,
                             int* __restrict__ offsets, int* __restrict__ bsums) {
  __shared__ int s[SCAN_B];
  int t = threadIdx.x;
  int i = blockIdx.x * SCAN_B + t;
  int v = (i < NP) ? counts[i] : 0;
  s[t] = v;
  __syncthreads();
  for (int off = 1; off < SCAN_B; off <<= 1) {
    int a = (t >= off) ? s[t - off] : 0;
    __syncthreads();
    s[t] += a;
    __syncthreads();
  }
  if (i < NP) offsets[i] = s[t] - v;
  if (t == SCAN_B - 1) bsums[blockIdx.x] = s[t];
}

__global__ void scan2_kernel(int* __restrict__ bsums) {
  __shared__ int s[512];
  int t = threadIdx.x;
  int v = (t < NBLK) ? bsums[t] : 0;
  s[t] = v;
  __syncthreads();
  for (int off = 1; off < 512; off <<= 1) {
    int a = (t >= off) ? s[t - off] : 0;
    __syncthreads();
    s[t] += a;
    __syncthreads();
  }
  if (t < NBLK) bsums[t] = s[t] - v;
}

__global__ void scan3_kernel(int* __restrict__ offsets,
                             const int* __restrict__ bsums,
                             int* __restrict__ cursor) {
  int i = blockIdx.x * SCAN_B + threadIdx.x;
  if (i >= NP) return;
  int o = offsets[i] + bsums[blockIdx.x];
  offsets[i] = o;
  cursor[i] = o;
}

__global__ void scatter_kernel(const int* __restrict__ ei,
                               int* __restrict__ cursor, int* __restrict__ csr_src) {
  int i = blockIdx.x * 256 + threadIdx.x;   // 4 edges per thread
  if (i >= NE / 4) return;
  int4 s = reinterpret_cast<const int4*>(ei)[i];
  int4 d = reinterpret_cast<const int4*>(ei + NE)[i];
  csr_src[atomicAdd(&cursor[d.x], 1)] = s.x;
  csr_src[atomicAdd(&cursor[d.y], 1)] = s.y;
  csr_src[atomicAdd(&cursor[d.z], 1)] = s.z;
  csr_src[atomicAdd(&cursor[d.w], 1)] = s.w;
}

// ---------------- edge messages ----------------
// Per node: h1d (dst-half, split, once) -> per 16-edge group: layer1 (src x in
// single bf16 -- per-edge-independent error, aggregates as sqrt(cnt)) +
// layer2 (split P -- node-coherent, must stay exact); relu(e) accumulated
// per-lane in f32; layer3 deferred to once per node. Next group's src rows
// prefetched before the current group's MFMA chain (latency hiding).
template <bool PREQ>
__global__ __launch_bounds__(256, 3) void edge_mfma_kernel(
    const float* __restrict__ x, const short* __restrict__ xh,
    const short* __restrict__ xl, const short* __restrict__ wqs,
    const int* __restrict__ counts, const int* __restrict__ offsets,
    const int* __restrict__ csr_src,
    const float* __restrict__ mW1, const float* __restrict__ mb1,
    const float* __restrict__ mW2, const float* __restrict__ mb2,
    const float* __restrict__ mW3, const float* __restrict__ mb3,
    float* __restrict__ msg) {
  const int lane = threadIdx.x & 63;
  const int l15 = lane & 15;
  const int lq = lane >> 4;
  const int wid = (blockIdx.x * 256 + threadIdx.x) >> 6;
  const int nw = gridDim.x * 4;
  const v8s* wq = reinterpret_cast<const v8s*>(wqs);

  // resident weights: layer1-src + layer2 (48 VGPR)
  v8s w1sh[2][2], w1sl[2][2], w2h[2], w2l[2];
#pragma unroll
  for (int t = 0; t < 2; ++t)
#pragma unroll
    for (int kc = 0; kc < 2; ++kc) {
      if constexpr (PREQ) {
        w1sh[t][kc] = wq[(t * 2 + kc) * 64 + lane];
        w1sl[t][kc] = wq[(4 + t * 2 + kc) * 64 + lane];
      } else {
        load_wfrag(mW1, HID, kc * 32, t * 16, lq, l15, &w1sh[t][kc], &w1sl[t][kc]);
      }
    }
#pragma unroll
  for (int t = 0; t < 2; ++t) {
    if constexpr (PREQ) {
      w2h[t] = wq[(16 + t) * 64 + lane];
      w2l[t] = wq[(18 + t) * 64 + lane];
    } else {
      load_wfrag(mW2, HID, 0, t * 16, lq, l15, &w2h[t], &w2l[t]);
    }
  }

  for (int n = wid; n < NP; n += nw) {
    const int cnt = counts[n];
    const int off = offsets[n];
    const int ng = (cnt + 15) >> 4;

    // dst-half of layer1 + bias, once per node (w1d frags scoped here)
    v4f h1d0 = *reinterpret_cast<const v4f*>(mb1 + 4 * lq);
    v4f h1d1 = *reinterpret_cast<const v4f*>(mb1 + 16 + 4 * lq);
#pragma unroll
    for (int kc = 0; kc < 2; ++kc) {
      v8s xhf, xlf;
      if constexpr (PREQ) {
        xhf = ldfrag(xh + (size_t)n * SD, kc * 32, lq);
        xlf = ldfrag(xl + (size_t)n * SD, kc * 32, lq);
      } else {
        load_xfrag(x + (size_t)n * SD, kc * 32, lq, &xhf, &xlf);
      }
#pragma unroll
      for (int t = 0; t < 2; ++t) {
        v8s dh, dl;
        if constexpr (PREQ) {
          dh = wq[(8 + t * 2 + kc) * 64 + lane];
          dl = wq[(12 + t * 2 + kc) * 64 + lane];
        } else {
          load_wfrag(mW1, HID, 64 + kc * 32, t * 16, lq, l15, &dh, &dl);
        }
        if (t == 0) h1d0 = mfma3(dh, dl, xhf, xlf, h1d0);
        else        h1d1 = mfma3(dh, dl, xhf, xlf, h1d1);
      }
    }

    v4f r0 = {0.f, 0.f, 0.f, 0.f}, r1 = {0.f, 0.f, 0.f, 0.f};

    int rem = cnt;
    bool vcur = l15 < rem;
    int scur = vcur ? csr_src[off + l15] : n;
    v8s cx0, cx1;
    if constexpr (PREQ) {
      cx0 = ldfrag(xh + (size_t)scur * SD, 0, lq);
      cx1 = ldfrag(xh + (size_t)scur * SD, 32, lq);
    } else {
      cx0 = load_xfrag_hi(x + (size_t)scur * SD, 0, lq);
      cx1 = load_xfrag_hi(x + (size_t)scur * SD, 32, lq);
    }

    for (int g = 0; g < ng; ++g) {
      // prefetch next group's src rows before computing on current
      int rem2 = rem - 16;
      bool vnxt = l15 < rem2;
      int snxt = vnxt ? csr_src[off + (g + 1) * 16 + l15] : n;
      v8s nx0, nx1;
      if constexpr (PREQ) {
        nx0 = ldfrag(xh + (size_t)snxt * SD, 0, lq);
        nx1 = ldfrag(xh + (size_t)snxt * SD, 32, lq);
      } else {
        nx0 = load_xfrag_hi(x + (size_t)snxt * SD, 0, lq);
        nx1 = load_xfrag_hi(x + (size_t)snxt * SD, 32, lq);
      }

      // layer 1 (src half): (w_hi + w_lo) * x_hi -> 8 MFMA
      v4f d0 = h1d0, d1 = h1d1;
      d0 = MFMA32(w1sh[0][0], cx0, d0);
      d0 = MFMA32(w1sl[0][0], cx0, d0);
      d0 = MFMA32(w1sh[0][1], cx1, d0);
      d0 = MFMA32(w1sl[0][1], cx1, d0);
      d1 = MFMA32(w1sh[1][0], cx0, d1);
      d1 = MFMA32(w1sl[1][0], cx0, d1);
      d1 = MFMA32(w1sh[1][1], cx1, d1);
      d1 = MFMA32(w1sl[1][1], cx1, d1);

      // layer 2 (split P, node-coherent)
      v8s ph, pl;
      chain_frag(d0, d1, &ph, &pl);
      v4f e0 = *reinterpret_cast<const v4f*>(mb2 + 4 * lq);
      v4f e1 = *reinterpret_cast<const v4f*>(mb2 + 16 + 4 * lq);
      e0 = mfma3(w2h[0], w2l[0], ph, pl, e0);
      e1 = mfma3(w2h[1], w2l[1], ph, pl, e1);

      if (vcur) {
#pragma unroll
        for (int j = 0; j < 4; ++j) {
          r0[j] += fmaxf(e0[j], 0.f);
          r1[j] += fmaxf(e1[j], 0.f);
        }
      }
      cx0 = nx0;
      cx1 = nx1;
      vcur = vnxt;
      rem = rem2;
    }

    // reduce relu-sums over the 16 slot-columns (xor broadcast to all lanes)
#pragma unroll
    for (int j = 0; j < 4; ++j) {
      float a = r0[j], b = r1[j];
      a += __shfl_xor(a, 1); a += __shfl_xor(a, 2);
      a += __shfl_xor(a, 4); a += __shfl_xor(a, 8);
      b += __shfl_xor(b, 1); b += __shfl_xor(b, 2);
      b += __shfl_xor(b, 4); b += __shfl_xor(b, 8);
      r0[j] = a; r1[j] = b;
    }
    // quantize summed r once (split) -> single B-frag, uniform across columns
    v8s bh, bl;
#pragma unroll
    for (int j = 0; j < 4; ++j) {
      short h0 = f2bf(r0[j]); bh[j] = h0;     bl[j] = f2bf(r0[j] - bf2f(h0));
      short h1 = f2bf(r1[j]); bh[j + 4] = h1; bl[j + 4] = f2bf(r1[j] - bf2f(h1));
    }
    float fc = (float)cnt;
#pragma unroll
    for (int t = 0; t < 4; ++t) {
      v8s ah, al;
      if constexpr (PREQ) {
        ah = wq[(20 + t) * 64 + lane];
        al = wq[(24 + t) * 64 + lane];
      } else {
        load_wfrag(mW3, MSG, 0, t * 16, lq, l15, &ah, &al);
      }
      v4f c = {0.f, 0.f, 0.f, 0.f};
      c = mfma3(ah, al, bh, bl, c);
      if (l15 == 0) {
        v4f o;
#pragma unroll
        for (int q = 0; q < 4; ++q)
          o[q] = c[q] + fc * mb3[t * 16 + 4 * lq + q];
        *reinterpret_cast<v4f*>(msg + (size_t)n * MSG + t * 16 + 4 * lq) = o;
      }
    }
  }
}

// ---------------- node update (16 nodes/wave) ----------------
// msg aliases out: every store data-depends on all of the wave's msg reads.
template <bool PREQ>
__global__ __launch_bounds__(256, 2) void node_mfma_kernel(
    const float* __restrict__ x, const short* __restrict__ xh,
    const short* __restrict__ xl, const short* __restrict__ wqs,
    const float* msg,
    const float* __restrict__ oW1, const float* __restrict__ ob1,
    const float* __restrict__ oW2, const float* __restrict__ ob2,
    const float* __restrict__ oW3, const float* __restrict__ ob3,
    float* out) {
  const int lane = threadIdx.x & 63;
  const int l15 = lane & 15;
  const int lq = lane >> 4;
  const int tile = (blockIdx.x * 256 + threadIdx.x) >> 6;
  if (tile >= NP / 16) return;   // NP % 16 == 0
  const v8s* wq = reinterpret_cast<const v8s*>(wqs);

  v8s w1h[2][4], w1l[2][4], w2h[2], w2l[2], w3h[4], w3l[4];
#pragma unroll
  for (int t = 0; t < 2; ++t)
#pragma unroll
    for (int kc = 0; kc < 4; ++kc) {
      if constexpr (PREQ) {
        w1h[t][kc] = wq[(28 + t * 4 + kc) * 64 + lane];
        w1l[t][kc] = wq[(36 + t * 4 + kc) * 64 + lane];
      } else {
        load_wfrag(oW1, HID, kc * 32, t * 16, lq, l15, &w1h[t][kc], &w1l[t][kc]);
      }
    }
#pragma unroll
  for (int t = 0; t < 2; ++t) {
    if constexpr (PREQ) {
      w2h[t] = wq[(44 + t) * 64 + lane];
      w2l[t] = wq[(46 + t) * 64 + lane];
    } else {
      load_wfrag(oW2, HID, 0, t * 16, lq, l15, &w2h[t], &w2l[t]);
    }
  }
#pragma unroll
  for (int t = 0; t < 4; ++t) {
    if constexpr (PREQ) {
      w3h[t] = wq[(48 + t) * 64 + lane];
      w3l[t] = wq[(52 + t) * 64 + lane];
    } else {
      load_wfrag(oW3, SD, 0, t * 16, lq, l15, &w3h[t], &w3l[t]);
    }
  }

  const int node = tile * 16 + l15;
  const float* mn = msg + (size_t)node * MSG;

  v4f d0 = *reinterpret_cast<const v4f*>(ob1 + 4 * lq);
  v4f d1 = *reinterpret_cast<const v4f*>(ob1 + 16 + 4 * lq);
#pragma unroll
  for (int kc = 0; kc < 2; ++kc) {
    v8s xhf, xlf;
    if constexpr (PREQ) {
      xhf = ldfrag(xh + (size_t)node * SD, kc * 32, lq);
      xlf = ldfrag(xl + (size_t)node * SD, kc * 32, lq);
    } else {
      load_xfrag(x + (size_t)node * SD, kc * 32, lq, &xhf, &xlf);
    }
    d0 = mfma3(w1h[0][kc], w1l[0][kc], xhf, xlf, d0);
    d1 = mfma3(w1h[1][kc], w1l[1][kc], xhf, xlf, d1);
  }
#pragma unroll
  for (int kc = 0; kc < 2; ++kc) {
    v8s xhf, xlf;
    load_xfrag(mn, kc * 32, lq, &xhf, &xlf);   // msg is f32 (aliases out)
    d0 = mfma3(w1h[0][2 + kc], w1l[0][2 + kc], xhf, xlf, d0);
    d1 = mfma3(w1h[1][2 + kc], w1l[1][2 + kc], xhf, xlf, d1);
  }

  v8s ph, pl;
  chain_frag(d0, d1, &ph, &pl);
  v4f e0 = *reinterpret_cast<const v4f*>(ob2 + 4 * lq);
  v4f e1 = *reinterpret_cast<const v4f*>(ob2 + 16 + 4 * lq);
  e0 = mfma3(w2h[0], w2l[0], ph, pl, e0);
  e1 = mfma3(w2h[1], w2l[1], ph, pl, e1);

  v8s rh, rl;
  chain_frag(e0, e1, &rh, &rl);

  float* orow = out + (size_t)node * SD;
#pragma unroll
  for (int t = 0; t < 4; ++t) {
    v4f c = *reinterpret_cast<const v4f*>(ob3 + t * 16 + 4 * lq);
    c = mfma3(w3h[t], w3l[t], rh, rl, c);
    *reinterpret_cast<v4f*>(orow + t * 16 + 4 * lq) = c;
  }
}

extern "C" void kernel_launch(void* const* d_in, const int* in_sizes, int n_in,
                              void* d_out, int out_size, void* d_ws,
                              size_t ws_size, hipStream_t stream) {
  const float* x = (const float*)d_in[0];
  const int* ei = (const int*)d_in[1];
  const float* mW1 = (const float*)d_in[2];
  const float* mb1 = (const float*)d_in[3];
  const float* mW2 = (const float*)d_in[4];
  const float* mb2 = (const float*)d_in[5];
  const float* mW3 = (const float*)d_in[6];
  const float* mb3 = (const float*)d_in[7];
  const float* oW1 = (const float*)d_in[8];
  const float* ob1 = (const float*)d_in[9];
  const float* oW2 = (const float*)d_in[10];
  const float* ob2 = (const float*)d_in[11];
  const float* oW3 = (const float*)d_in[12];
  const float* ob3 = (const float*)d_in[13];
  float* out = (float*)d_out;

  const size_t xq_elems = (size_t)NP * SD;                 // shorts per array
  const size_t wq_bytes = (size_t)WQ_FRAGS * 64 * 16;      // 56 KiB
  const size_t int_bytes = ((size_t)3 * NP_PAD + 512 + NE) * 4;
  const size_t preq_bytes = 2 * xq_elems * 2 + wq_bytes + int_bytes;
  const bool preq = ws_size >= preq_bytes;

  short* xh = nullptr;
  short* xl = nullptr;
  short* wqs = nullptr;
  int* ints;
  if (preq) {
    xh = (short*)d_ws;
    xl = xh + xq_elems;
    wqs = xl + xq_elems;
    ints = (int*)((char*)wqs + wq_bytes);
  } else {
    ints = (int*)d_ws;
  }
  int* counts = ints;
  int* offsets = counts + NP_PAD;
  int* cursor = offsets + NP_PAD;
  int* bsums = cursor + NP_PAD;
  int* csr_src = bsums + 512;

  float* msg = out;   // msg aliases d_out (RAW-safe in node kernel)

  hipMemsetAsync(counts, 0, NP_PAD * sizeof(int), stream);

  if (preq) {
    preq_kernel<<<(NP * SD / 4 + 255) / 256, 256, 0, stream>>>(x, xh, xl);
    prew_kernel<<<1, 64, 0, stream>>>(mW1, mW2, mW3, oW1, oW2, oW3, wqs);
  }

  hist_kernel<<<(NE / 4 + 255) / 256, 256, 0, stream>>>(ei, counts);
  scan1_kernel<<<NBLK, SCAN_B, 0, stream>>>(counts, offsets, bsums);
  scan2_kernel<<<1, 512, 0, stream>>>(bsums);
  scan3_kernel<<<NBLK, SCAN_B, 0, stream>>>(offsets, bsums, cursor);
  scatter_kernel<<<(NE / 4 + 255) / 256, 256, 0, stream>>>(ei, cursor, csr_src);

  if (preq) {
    edge_mfma_kernel<true><<<2048, 256, 0, stream>>>(
        x, xh, xl, wqs, counts, offsets, csr_src,
        mW1, mb1, mW2, mb2, mW3, mb3, msg);
    node_mfma_kernel<true><<<(NP / 16 + 3) / 4, 256, 0, stream>>>(
        x, xh, xl, wqs, msg, oW1, ob1, oW2, ob2, oW3, ob3, out);
  } else {
    edge_mfma_kernel<false><<<2048, 256, 0, stream>>>(
        x, xh, xl, wqs, counts, offsets, csr_src,
        mW1, mb1, mW2, mb2, mW3, mb3, msg);
    node_mfma_kernel<false><<<(NP / 16 + 3) / 4, 256, 0, stream>>>(
        x, xh, xl, wqs, msg, oW1, ob1, oW2, ob2, oW3, ob3, out);
  }
}

// Round 8
// 354.119 us; speedup vs baseline: 15.8124x; 1.4145x over previous
//
#include <hip/hip_runtime.h>

#define NP 100000
#define NE 1600000
#define SD 64      // STATE_DIM
#define HID 32
#define MSG 64
#define NP_PAD 100352
#define SCAN_B 256
#define NBLK ((NP + SCAN_B - 1) / SCAN_B)   // 391
#define NTILE (NP / 16)                     // 6250 (NP % 16 == 0)

typedef float v4f __attribute__((ext_vector_type(4)));
typedef short v4s __attribute__((ext_vector_type(4)));
typedef short v8s __attribute__((ext_vector_type(8)));
typedef __bf16 v8bf __attribute__((ext_vector_type(8)));

// weight-frag ids (each frag = 64 lanes x v8s = 1 KiB):
// edge MLP: 0-3 w1s hi [t*2+kc], 4-7 w1s lo, 8-11 w1d hi [t*2+kc], 12-15 w1d lo,
//           16-17 w2 hi[t], 18-19 w2 lo, 20-23 w3 hi[t], 24-27 w3 lo
// node MLP: 28-35 oW1 hi [t*4+kc], 36-43 oW1 lo, 44-45 oW2 hi, 46-47 oW2 lo,
//           48-51 oW3 hi[t], 52-55 oW3 lo
#define WQ_FRAGS 56

__device__ __forceinline__ v4f MFMA32(v8s a, v8s b, v4f c) {
  return __builtin_amdgcn_mfma_f32_16x16x32_bf16(
      __builtin_bit_cast(v8bf, a), __builtin_bit_cast(v8bf, b), c, 0, 0, 0);
}

__device__ __forceinline__ short f2bf(float f) {
  unsigned u = __builtin_bit_cast(unsigned, f);
  u += 0x7FFFu + ((u >> 16) & 1u);   // RNE
  return (short)(u >> 16);
}
__device__ __forceinline__ float bf2f(short s) {
  unsigned u = ((unsigned)(unsigned short)s) << 16;
  return __builtin_bit_cast(float, u);
}

// 3-term split-bf16 product: C += Ah*Bh + Ah*Bl + Al*Bh (error ~2^-17 rel)
__device__ __forceinline__ v4f mfma3(v8s ah, v8s al, v8s bh, v8s bl, v4f c) {
  c = MFMA32(al, bh, c);
  c = MFMA32(ah, bl, c);
  c = MFMA32(ah, bh, c);
  return c;
}

// A-frag (hi/lo) from row-major W[K][ld]: A[m][k] = W[k][m0+l15]
__device__ __forceinline__ void load_wfrag(const float* __restrict__ W, int ld,
                                           int kb, int m0, int lq, int l15,
                                           v8s* hi, v8s* lo) {
  v8s h, l;
#pragma unroll
  for (int j = 0; j < 8; ++j) {
    int k = kb + ((j < 4) ? (4 * lq + j) : (16 + 4 * lq + (j - 4)));
    float v = W[k * ld + m0 + l15];
    short hb = f2bf(v);
    h[j] = hb;
    l[j] = f2bf(v - bf2f(hb));
  }
  *hi = h;
  *lo = l;
}

// split two v4f halves into one split B-frag (no relu)
__device__ __forceinline__ void split8(v4f a, v4f b, v8s* hi, v8s* lo) {
  v8s h, l;
#pragma unroll
  for (int j = 0; j < 4; ++j) {
    short ha = f2bf(a[j]); h[j] = ha; l[j] = f2bf(a[j] - bf2f(ha));
    short hb = f2bf(b[j]); h[j + 4] = hb; l[j + 4] = f2bf(b[j] - bf2f(hb));
  }
  *hi = h;
  *lo = l;
}

// B-frag (hi/lo) from an f32 feature row
__device__ __forceinline__ void load_xfrag(const float* xs, int kb, int lq,
                                           v8s* hi, v8s* lo) {
  v4f a = *reinterpret_cast<const v4f*>(xs + kb + 4 * lq);
  v4f b = *reinterpret_cast<const v4f*>(xs + kb + 16 + 4 * lq);
  split8(a, b, hi, lo);
}

// hi-only B-frag from an f32 feature row (fallback src gather)
__device__ __forceinline__ v8s load_xfrag_hi(const float* xs, int kb, int lq) {
  v4f a = *reinterpret_cast<const v4f*>(xs + kb + 4 * lq);
  v4f b = *reinterpret_cast<const v4f*>(xs + kb + 16 + 4 * lq);
  v8s h;
#pragma unroll
  for (int j = 0; j < 4; ++j) {
    h[j] = f2bf(a[j]);
    h[j + 4] = f2bf(b[j]);
  }
  return h;
}

// B-frag from a prequantized short row: two dwordx2 loads, zero VALU
__device__ __forceinline__ v8s ldfrag(const short* row, int kb, int lq) {
  v4s a = *reinterpret_cast<const v4s*>(row + kb + 4 * lq);
  v4s b = *reinterpret_cast<const v4s*>(row + kb + 16 + 4 * lq);
  return __builtin_shufflevector(a, b, 0, 1, 2, 3, 4, 5, 6, 7);
}

// D blocks -> next-layer split B-frag with relu
__device__ __forceinline__ void chain_frag(v4f d0, v4f d1, v8s* hi, v8s* lo) {
  v4f a, b;
#pragma unroll
  for (int j = 0; j < 4; ++j) {
    a[j] = fmaxf(d0[j], 0.f);
    b[j] = fmaxf(d1[j], 0.f);
  }
  split8(a, b, hi, lo);
}

// ---------------- prequantization ----------------

__global__ void preq_kernel(const float* __restrict__ x, short* __restrict__ xh) {
  int i = blockIdx.x * 256 + threadIdx.x;   // one thread per 4 values
  if (i >= NP * SD / 4) return;
  v4f v = reinterpret_cast<const v4f*>(x)[i];
  v4s h;
#pragma unroll
  for (int j = 0; j < 4; ++j) h[j] = f2bf(v[j]);
  reinterpret_cast<v4s*>(xh)[i] = h;
}

__global__ void prew_kernel(const float* __restrict__ mW1,
                            const float* __restrict__ mW2,
                            const float* __restrict__ mW3,
                            const float* __restrict__ oW1,
                            const float* __restrict__ oW2,
                            const float* __restrict__ oW3,
                            short* __restrict__ wqs) {
  int lane = threadIdx.x;   // 64 threads, 1 block
  int l15 = lane & 15, lq = lane >> 4;
  v8s* wq = reinterpret_cast<v8s*>(wqs);
  v8s h, l;
#pragma unroll
  for (int t = 0; t < 2; ++t)
#pragma unroll
    for (int kc = 0; kc < 2; ++kc) {
      load_wfrag(mW1, HID, kc * 32, t * 16, lq, l15, &h, &l);
      wq[(t * 2 + kc) * 64 + lane] = h;
      wq[(4 + t * 2 + kc) * 64 + lane] = l;
      load_wfrag(mW1, HID, 64 + kc * 32, t * 16, lq, l15, &h, &l);
      wq[(8 + t * 2 + kc) * 64 + lane] = h;
      wq[(12 + t * 2 + kc) * 64 + lane] = l;
    }
#pragma unroll
  for (int t = 0; t < 2; ++t) {
    load_wfrag(mW2, HID, 0, t * 16, lq, l15, &h, &l);
    wq[(16 + t) * 64 + lane] = h;
    wq[(18 + t) * 64 + lane] = l;
  }
#pragma unroll
  for (int t = 0; t < 4; ++t) {
    load_wfrag(mW3, MSG, 0, t * 16, lq, l15, &h, &l);
    wq[(20 + t) * 64 + lane] = h;
    wq[(24 + t) * 64 + lane] = l;
  }
#pragma unroll
  for (int t = 0; t < 2; ++t)
#pragma unroll
    for (int kc = 0; kc < 4; ++kc) {
      load_wfrag(oW1, HID, kc * 32, t * 16, lq, l15, &h, &l);
      wq[(28 + t * 4 + kc) * 64 + lane] = h;
      wq[(36 + t * 4 + kc) * 64 + lane] = l;
    }
#pragma unroll
  for (int t = 0; t < 2; ++t) {
    load_wfrag(oW2, HID, 0, t * 16, lq, l15, &h, &l);
    wq[(44 + t) * 64 + lane] = h;
    wq[(46 + t) * 64 + lane] = l;
  }
#pragma unroll
  for (int t = 0; t < 4; ++t) {
    load_wfrag(oW3, SD, 0, t * 16, lq, l15, &h, &l);
    wq[(48 + t) * 64 + lane] = h;
    wq[(52 + t) * 64 + lane] = l;
  }
}

// ---------------- CSR build ----------------

__global__ void hist_kernel(const int* __restrict__ ei, int* __restrict__ counts) {
  int i = blockIdx.x * 256 + threadIdx.x;   // 4 edges per thread
  if (i >= NE / 4) return;
  int4 d = reinterpret_cast<const int4*>(ei + NE)[i];
  atomicAdd(&counts[d.x], 1);
  atomicAdd(&counts[d.y], 1);
  atomicAdd(&counts[d.z], 1);
  atomicAdd(&counts[d.w], 1);
}

__global__ void scan1_kernel(const int* __restrict__ counts,
                             int* __restrict__ offsets, int* __restrict__ bsums) {
  __shared__ int s[SCAN_B];
  int t = threadIdx.x;
  int i = blockIdx.x * SCAN_B + t;
  int v = (i < NP) ? counts[i] : 0;
  s[t] = v;
  __syncthreads();
  for (int off = 1; off < SCAN_B; off <<= 1) {
    int a = (t >= off) ? s[t - off] : 0;
    __syncthreads();
    s[t] += a;
    __syncthreads();
  }
  if (i < NP) offsets[i] = s[t] - v;
  if (t == SCAN_B - 1) bsums[blockIdx.x] = s[t];
}

__global__ void scan2_kernel(int* __restrict__ bsums) {
  __shared__ int s[512];
  int t = threadIdx.x;
  int v = (t < NBLK) ? bsums[t] : 0;
  s[t] = v;
  __syncthreads();
  for (int off = 1; off < 512; off <<= 1) {
    int a = (t >= off) ? s[t - off] : 0;
    __syncthreads();
    s[t] += a;
    __syncthreads();
  }
  if (t < NBLK) bsums[t] = s[t] - v;
}

__global__ void scan3_kernel(int* __restrict__ offsets,
                             const int* __restrict__ bsums,
                             int* __restrict__ cursor) {
  int i = blockIdx.x * SCAN_B + threadIdx.x;
  if (i >= NP) return;
  int o = offsets[i] + bsums[blockIdx.x];
  offsets[i] = o;
  cursor[i] = o;
}

__global__ void scatter_kernel(const int* __restrict__ ei,
                               int* __restrict__ cursor, int* __restrict__ csr_src) {
  int i = blockIdx.x * 256 + threadIdx.x;   // 4 edges per thread
  if (i >= NE / 4) return;
  int4 s = reinterpret_cast<const int4*>(ei)[i];
  int4 d = reinterpret_cast<const int4*>(ei + NE)[i];
  csr_src[atomicAdd(&cursor[d.x], 1)] = s.x;
  csr_src[atomicAdd(&cursor[d.y], 1)] = s.y;
  csr_src[atomicAdd(&cursor[d.z], 1)] = s.z;
  csr_src[atomicAdd(&cursor[d.w], 1)] = s.w;
}

// ---------------- batched h1d: 16 nodes/wave (full column utilization) ----------------
// h1d[node][u] = mb1[u] + sum_k mW1[64+k][u] * x[node][k]  (split-bf16 exact)
template <bool PREQ>
__global__ __launch_bounds__(256, 2) void h1d_kernel(
    const float* __restrict__ x, const short* __restrict__ wqs,
    const float* __restrict__ mW1, const float* __restrict__ mb1,
    float* __restrict__ h1d_buf) {
  const int lane = threadIdx.x & 63;
  const int l15 = lane & 15;
  const int lq = lane >> 4;
  const int tile = (blockIdx.x * 256 + threadIdx.x) >> 6;
  if (tile >= NTILE) return;
  const v8s* wq = reinterpret_cast<const v8s*>(wqs);

  const int node = tile * 16 + l15;
  v4f d0, d1;
#pragma unroll
  for (int q = 0; q < 4; ++q) {
    d0[q] = mb1[4 * lq + q];
    d1[q] = mb1[16 + 4 * lq + q];
  }
#pragma unroll
  for (int kc = 0; kc < 2; ++kc) {
    v8s xhf, xlf;
    load_xfrag(x + (size_t)node * SD, kc * 32, lq, &xhf, &xlf);
    v8s h0, l0, h1, l1;
    if constexpr (PREQ) {
      h0 = wq[(8 + kc) * 64 + lane];
      l0 = wq[(12 + kc) * 64 + lane];
      h1 = wq[(10 + kc) * 64 + lane];
      l1 = wq[(14 + kc) * 64 + lane];
    } else {
      load_wfrag(mW1, HID, 64 + kc * 32, 0, lq, l15, &h0, &l0);
      load_wfrag(mW1, HID, 64 + kc * 32, 16, lq, l15, &h1, &l1);
    }
    d0 = mfma3(h0, l0, xhf, xlf, d0);
    d1 = mfma3(h1, l1, xhf, xlf, d1);
  }
  *reinterpret_cast<v4f*>(h1d_buf + (size_t)node * HID + 4 * lq) = d0;
  *reinterpret_cast<v4f*>(h1d_buf + (size_t)node * HID + 16 + 4 * lq) = d1;
}

// ---------------- edge loop: group gather + layers 1-2 only ----------------
template <bool PREQ>
__global__ __launch_bounds__(256, 3) void edge_mfma_kernel(
    const float* __restrict__ x, const short* __restrict__ xh,
    const short* __restrict__ wqs, const float* __restrict__ h1d_buf,
    const int* __restrict__ counts, const int* __restrict__ offsets,
    const int* __restrict__ csr_src,
    const float* __restrict__ mW1, const float* __restrict__ mW2,
    const float* __restrict__ mb2,
    float* __restrict__ rsum) {
  const int lane = threadIdx.x & 63;
  const int l15 = lane & 15;
  const int lq = lane >> 4;
  const int wid = (blockIdx.x * 256 + threadIdx.x) >> 6;
  const int nw = gridDim.x * 4;
  const v8s* wq = reinterpret_cast<const v8s*>(wqs);

  // resident weights: layer1-src + layer2 (48 VGPR)
  v8s w1sh[2][2], w1sl[2][2], w2h[2], w2l[2];
#pragma unroll
  for (int t = 0; t < 2; ++t)
#pragma unroll
    for (int kc = 0; kc < 2; ++kc) {
      if constexpr (PREQ) {
        w1sh[t][kc] = wq[(t * 2 + kc) * 64 + lane];
        w1sl[t][kc] = wq[(4 + t * 2 + kc) * 64 + lane];
      } else {
        load_wfrag(mW1, HID, kc * 32, t * 16, lq, l15, &w1sh[t][kc], &w1sl[t][kc]);
      }
    }
#pragma unroll
  for (int t = 0; t < 2; ++t) {
    if constexpr (PREQ) {
      w2h[t] = wq[(16 + t) * 64 + lane];
      w2l[t] = wq[(18 + t) * 64 + lane];
    } else {
      load_wfrag(mW2, HID, 0, t * 16, lq, l15, &w2h[t], &w2l[t]);
    }
  }

  for (int n = wid; n < NP; n += nw) {
    const int cnt = counts[n];
    const int off = offsets[n];
    const int ng = (cnt + 15) >> 4;

    // precomputed dst-half (broadcast load, all 16 columns identical)
    v4f h1d0 = *reinterpret_cast<const v4f*>(h1d_buf + (size_t)n * HID + 4 * lq);
    v4f h1d1 = *reinterpret_cast<const v4f*>(h1d_buf + (size_t)n * HID + 16 + 4 * lq);

    v4f r0 = {0.f, 0.f, 0.f, 0.f}, r1 = {0.f, 0.f, 0.f, 0.f};

    int rem = cnt;
    bool vcur = l15 < rem;
    int scur = vcur ? csr_src[off + l15] : n;
    v8s cx0, cx1;
    if constexpr (PREQ) {
      cx0 = ldfrag(xh + (size_t)scur * SD, 0, lq);
      cx1 = ldfrag(xh + (size_t)scur * SD, 32, lq);
    } else {
      cx0 = load_xfrag_hi(x + (size_t)scur * SD, 0, lq);
      cx1 = load_xfrag_hi(x + (size_t)scur * SD, 32, lq);
    }

    for (int g = 0; g < ng; ++g) {
      // prefetch next group's src rows before computing on current
      int rem2 = rem - 16;
      bool vnxt = l15 < rem2;
      int snxt = vnxt ? csr_src[off + (g + 1) * 16 + l15] : n;
      v8s nx0, nx1;
      if constexpr (PREQ) {
        nx0 = ldfrag(xh + (size_t)snxt * SD, 0, lq);
        nx1 = ldfrag(xh + (size_t)snxt * SD, 32, lq);
      } else {
        nx0 = load_xfrag_hi(x + (size_t)snxt * SD, 0, lq);
        nx1 = load_xfrag_hi(x + (size_t)snxt * SD, 32, lq);
      }

      // layer 1 (src half): (w_hi + w_lo) * x_hi -> 8 MFMA
      v4f d0 = h1d0, d1 = h1d1;
      d0 = MFMA32(w1sh[0][0], cx0, d0);
      d0 = MFMA32(w1sl[0][0], cx0, d0);
      d0 = MFMA32(w1sh[0][1], cx1, d0);
      d0 = MFMA32(w1sl[0][1], cx1, d0);
      d1 = MFMA32(w1sh[1][0], cx0, d1);
      d1 = MFMA32(w1sl[1][0], cx0, d1);
      d1 = MFMA32(w1sh[1][1], cx1, d1);
      d1 = MFMA32(w1sl[1][1], cx1, d1);

      // layer 2 (split P, node-coherent)
      v8s ph, pl;
      chain_frag(d0, d1, &ph, &pl);
      v4f e0 = *reinterpret_cast<const v4f*>(mb2 + 4 * lq);
      v4f e1 = *reinterpret_cast<const v4f*>(mb2 + 16 + 4 * lq);
      e0 = mfma3(w2h[0], w2l[0], ph, pl, e0);
      e1 = mfma3(w2h[1], w2l[1], ph, pl, e1);

      if (vcur) {
#pragma unroll
        for (int j = 0; j < 4; ++j) {
          r0[j] += fmaxf(e0[j], 0.f);
          r1[j] += fmaxf(e1[j], 0.f);
        }
      }
      cx0 = nx0;
      cx1 = nx1;
      vcur = vnxt;
      rem = rem2;
    }

    // reduce relu-sums over the 16 slot-columns
#pragma unroll
    for (int j = 0; j < 4; ++j) {
      float a = r0[j], b = r1[j];
      a += __shfl_xor(a, 1); a += __shfl_xor(a, 2);
      a += __shfl_xor(a, 4); a += __shfl_xor(a, 8);
      b += __shfl_xor(b, 1); b += __shfl_xor(b, 2);
      b += __shfl_xor(b, 4); b += __shfl_xor(b, 8);
      r0[j] = a; r1[j] = b;
    }
    if (l15 == 0) {
      *reinterpret_cast<v4f*>(rsum + (size_t)n * HID + 4 * lq) = r0;
      *reinterpret_cast<v4f*>(rsum + (size_t)n * HID + 16 + 4 * lq) = r1;
    }
  }
}

// ---------------- fused tail: edge layer3 + full node MLP, 16 nodes/wave ----
// msg D-layout (col=node, row=msg-dim) == node-layer1 B-frag layout for the
// msg half -> msg never touches memory.
template <bool PREQ>
__global__ __launch_bounds__(256, 2) void fused_tail_kernel(
    const float* __restrict__ x, const short* __restrict__ wqs,
    const float* __restrict__ rsum, const int* __restrict__ counts,
    const float* __restrict__ mW3, const float* __restrict__ mb3,
    const float* __restrict__ oW1, const float* __restrict__ ob1,
    const float* __restrict__ oW2, const float* __restrict__ ob2,
    const float* __restrict__ oW3, const float* __restrict__ ob3,
    float* __restrict__ out) {
  const int lane = threadIdx.x & 63;
  const int l15 = lane & 15;
  const int lq = lane >> 4;
  const int tile = (blockIdx.x * 256 + threadIdx.x) >> 6;
  if (tile >= NTILE) return;
  const v8s* wq = reinterpret_cast<const v8s*>(wqs);

  const int node = tile * 16 + l15;
  const float fc = (float)counts[node];

  // edge layer 3: msg = mW3^T r + fc*mb3
  v4f ra = *reinterpret_cast<const v4f*>(rsum + (size_t)node * HID + 4 * lq);
  v4f rb = *reinterpret_cast<const v4f*>(rsum + (size_t)node * HID + 16 + 4 * lq);
  v8s bh, bl;
  split8(ra, rb, &bh, &bl);

  v4f m[4];
#pragma unroll
  for (int t = 0; t < 4; ++t) {
    v8s ah, al;
    if constexpr (PREQ) {
      ah = wq[(20 + t) * 64 + lane];
      al = wq[(24 + t) * 64 + lane];
    } else {
      load_wfrag(mW3, MSG, 0, t * 16, lq, l15, &ah, &al);
    }
    v4f c = {0.f, 0.f, 0.f, 0.f};
    c = mfma3(ah, al, bh, bl, c);
#pragma unroll
    for (int q = 0; q < 4; ++q) c[q] += fc * mb3[t * 16 + 4 * lq + q];
    m[t] = c;
  }

  // node layer 1 on [x || msg]
  v4f d0 = *reinterpret_cast<const v4f*>(ob1 + 4 * lq);
  v4f d1 = *reinterpret_cast<const v4f*>(ob1 + 16 + 4 * lq);
#pragma unroll
  for (int kc = 0; kc < 2; ++kc) {
    v8s xhf, xlf;
    load_xfrag(x + (size_t)node * SD, kc * 32, lq, &xhf, &xlf);
    v8s h0, l0, h1, l1;
    if constexpr (PREQ) {
      h0 = wq[(28 + kc) * 64 + lane];
      l0 = wq[(36 + kc) * 64 + lane];
      h1 = wq[(32 + kc) * 64 + lane];
      l1 = wq[(40 + kc) * 64 + lane];
    } else {
      load_wfrag(oW1, HID, kc * 32, 0, lq, l15, &h0, &l0);
      load_wfrag(oW1, HID, kc * 32, 16, lq, l15, &h1, &l1);
    }
    d0 = mfma3(h0, l0, xhf, xlf, d0);
    d1 = mfma3(h1, l1, xhf, xlf, d1);
  }
  // msg half: B-frags directly from m[] registers (split, no relu)
#pragma unroll
  for (int kc = 0; kc < 2; ++kc) {
    v8s mh, ml;
    split8(m[kc * 2], m[kc * 2 + 1], &mh, &ml);
    v8s h0, l0, h1, l1;
    if constexpr (PREQ) {
      h0 = wq[(30 + kc) * 64 + lane];
      l0 = wq[(38 + kc) * 64 + lane];
      h1 = wq[(34 + kc) * 64 + lane];
      l1 = wq[(42 + kc) * 64 + lane];
    } else {
      load_wfrag(oW1, HID, 64 + kc * 32, 0, lq, l15, &h0, &l0);
      load_wfrag(oW1, HID, 64 + kc * 32, 16, lq, l15, &h1, &l1);
    }
    d0 = mfma3(h0, l0, mh, ml, d0);
    d1 = mfma3(h1, l1, mh, ml, d1);
  }

  // node layer 2
  v8s ph, pl;
  chain_frag(d0, d1, &ph, &pl);
  v4f e0 = *reinterpret_cast<const v4f*>(ob2 + 4 * lq);
  v4f e1 = *reinterpret_cast<const v4f*>(ob2 + 16 + 4 * lq);
  {
    v8s h0, l0, h1, l1;
    if constexpr (PREQ) {
      h0 = wq[44 * 64 + lane];
      l0 = wq[46 * 64 + lane];
      h1 = wq[45 * 64 + lane];
      l1 = wq[47 * 64 + lane];
    } else {
      load_wfrag(oW2, HID, 0, 0, lq, l15, &h0, &l0);
      load_wfrag(oW2, HID, 0, 16, lq, l15, &h1, &l1);
    }
    e0 = mfma3(h0, l0, ph, pl, e0);
    e1 = mfma3(h1, l1, ph, pl, e1);
  }

  // node layer 3 -> out
  v8s rh, rl;
  chain_frag(e0, e1, &rh, &rl);
  float* orow = out + (size_t)node * SD;
#pragma unroll
  for (int t = 0; t < 4; ++t) {
    v8s ah, al;
    if constexpr (PREQ) {
      ah = wq[(48 + t) * 64 + lane];
      al = wq[(52 + t) * 64 + lane];
    } else {
      load_wfrag(oW3, SD, 0, t * 16, lq, l15, &ah, &al);
    }
    v4f c;
#pragma unroll
    for (int q = 0; q < 4; ++q) c[q] = ob3[t * 16 + 4 * lq + q];
    c = mfma3(ah, al, rh, rl, c);
    *reinterpret_cast<v4f*>(orow + t * 16 + 4 * lq) = c;
  }
}

extern "C" void kernel_launch(void* const* d_in, const int* in_sizes, int n_in,
                              void* d_out, int out_size, void* d_ws,
                              size_t ws_size, hipStream_t stream) {
  const float* x = (const float*)d_in[0];
  const int* ei = (const int*)d_in[1];
  const float* mW1 = (const float*)d_in[2];
  const float* mb1 = (const float*)d_in[3];
  const float* mW2 = (const float*)d_in[4];
  const float* mb2 = (const float*)d_in[5];
  const float* mW3 = (const float*)d_in[6];
  const float* mb3 = (const float*)d_in[7];
  const float* oW1 = (const float*)d_in[8];
  const float* ob1 = (const float*)d_in[9];
  const float* oW2 = (const float*)d_in[10];
  const float* ob2 = (const float*)d_in[11];
  const float* oW3 = (const float*)d_in[12];
  const float* ob3 = (const float*)d_in[13];
  float* out = (float*)d_out;

  const size_t xq_bytes = (size_t)NP * SD * 2;             // 12.8 MB
  const size_t wq_bytes = (size_t)WQ_FRAGS * 64 * 16;      // 56 KiB
  const size_t buf_bytes = (size_t)NP * HID * 4;           // 12.8 MB each
  const size_t int_bytes = ((size_t)3 * NP_PAD + 512 + NE) * 4;   // 7.6 MB
  const size_t preq_bytes = xq_bytes + wq_bytes + 2 * buf_bytes + int_bytes;
  const bool preq = ws_size >= preq_bytes;

  char* p = (char*)d_ws;
  short* xh = nullptr;
  short* wqs = nullptr;
  if (preq) {
    xh = (short*)p; p += xq_bytes;
    wqs = (short*)p; p += wq_bytes;
  }
  float* h1d_buf = (float*)p; p += buf_bytes;
  float* rsum = (float*)p; p += buf_bytes;
  int* counts = (int*)p;
  int* offsets = counts + NP_PAD;
  int* cursor = offsets + NP_PAD;
  int* bsums = cursor + NP_PAD;
  int* csr_src = bsums + 512;

  hipMemsetAsync(counts, 0, NP_PAD * sizeof(int), stream);

  if (preq) {
    preq_kernel<<<(NP * SD / 4 + 255) / 256, 256, 0, stream>>>(x, xh);
    prew_kernel<<<1, 64, 0, stream>>>(mW1, mW2, mW3, oW1, oW2, oW3, wqs);
  }

  hist_kernel<<<(NE / 4 + 255) / 256, 256, 0, stream>>>(ei, counts);
  scan1_kernel<<<NBLK, SCAN_B, 0, stream>>>(counts, offsets, bsums);
  scan2_kernel<<<1, 512, 0, stream>>>(bsums);
  scan3_kernel<<<NBLK, SCAN_B, 0, stream>>>(offsets, bsums, cursor);
  scatter_kernel<<<(NE / 4 + 255) / 256, 256, 0, stream>>>(ei, cursor, csr_src);

  const int tile_blocks = (NTILE + 3) / 4;
  if (preq) {
    h1d_kernel<true><<<tile_blocks, 256, 0, stream>>>(x, wqs, mW1, mb1, h1d_buf);
    edge_mfma_kernel<true><<<2048, 256, 0, stream>>>(
        x, xh, wqs, h1d_buf, counts, offsets, csr_src, mW1, mW2, mb2, rsum);
    fused_tail_kernel<true><<<tile_blocks, 256, 0, stream>>>(
        x, wqs, rsum, counts, mW3, mb3, oW1, ob1, oW2, ob2, oW3, ob3, out);
  } else {
    h1d_kernel<false><<<tile_blocks, 256, 0, stream>>>(x, wqs, mW1, mb1, h1d_buf);
    edge_mfma_kernel<false><<<2048, 256, 0, stream>>>(
        x, xh, wqs, h1d_buf, counts, offsets, csr_src, mW1, mW2, mb2, rsum);
    fused_tail_kernel<false><<<tile_blocks, 256, 0, stream>>>(
        x, wqs, rsum, counts, mW3, mb3, oW1, ob1, oW2, ob2, oW3, ob3, out);
  }
}

// Round 9
// 173.433 us; speedup vs baseline: 32.2860x; 2.0418x over previous
//
#include <hip/hip_runtime.h>

#define NP 100000
#define NE 1600000
#define SD 64      // STATE_DIM
#define HID 32
#define MSG 64
#define NP_PAD 100352
#define NTILE (NP / 16)          // 6250
#define BINSZ 512
#define NBIN ((NP + BINSZ - 1) / BINSZ)   // 196
#define EPW 8192
#define NWG ((NE + EPW - 1) / EPW)        // 196

typedef float v4f __attribute__((ext_vector_type(4)));
typedef short v4s __attribute__((ext_vector_type(4)));
typedef short v8s __attribute__((ext_vector_type(8)));
typedef __bf16 v8bf __attribute__((ext_vector_type(8)));

// weight-frag ids (each frag = 64 lanes x v8s = 1 KiB):
// edge MLP: 0-3 w1s hi [t*2+kc], 4-7 w1s lo, 8-11 w1d hi [t*2+kc], 12-15 w1d lo,
//           16-17 w2 hi[t], 18-19 w2 lo, 20-23 w3 hi[t], 24-27 w3 lo
// node MLP: 28-35 oW1 hi [t*4+kc], 36-43 oW1 lo, 44-45 oW2 hi, 46-47 oW2 lo,
//           48-51 oW3 hi[t], 52-55 oW3 lo
#define WQ_FRAGS 56

__device__ __forceinline__ v4f MFMA32(v8s a, v8s b, v4f c) {
  return __builtin_amdgcn_mfma_f32_16x16x32_bf16(
      __builtin_bit_cast(v8bf, a), __builtin_bit_cast(v8bf, b), c, 0, 0, 0);
}

__device__ __forceinline__ short f2bf(float f) {   // HW RNE cvt
  return __builtin_bit_cast(short, (__bf16)f);
}
__device__ __forceinline__ float bf2f(short s) {
  unsigned u = ((unsigned)(unsigned short)s) << 16;
  return __builtin_bit_cast(float, u);
}

// 3-term split-bf16 product: C += Ah*Bh + Ah*Bl + Al*Bh (error ~2^-17 rel)
__device__ __forceinline__ v4f mfma3(v8s ah, v8s al, v8s bh, v8s bl, v4f c) {
  c = MFMA32(al, bh, c);
  c = MFMA32(ah, bl, c);
  c = MFMA32(ah, bh, c);
  return c;
}

// A-frag (hi/lo) from row-major W[K][ld]: A[m][k] = W[k][m0+l15]
__device__ __forceinline__ void load_wfrag(const float* __restrict__ W, int ld,
                                           int kb, int m0, int lq, int l15,
                                           v8s* hi, v8s* lo) {
  v8s h, l;
#pragma unroll
  for (int j = 0; j < 8; ++j) {
    int k = kb + ((j < 4) ? (4 * lq + j) : (16 + 4 * lq + (j - 4)));
    float v = W[k * ld + m0 + l15];
    short hb = f2bf(v);
    h[j] = hb;
    l[j] = f2bf(v - bf2f(hb));
  }
  *hi = h;
  *lo = l;
}

// split two v4f halves into one split B-frag (no relu)
__device__ __forceinline__ void split8(v4f a, v4f b, v8s* hi, v8s* lo) {
  v8s h, l;
#pragma unroll
  for (int j = 0; j < 4; ++j) {
    short ha = f2bf(a[j]); h[j] = ha; l[j] = f2bf(a[j] - bf2f(ha));
    short hb = f2bf(b[j]); h[j + 4] = hb; l[j + 4] = f2bf(b[j] - bf2f(hb));
  }
  *hi = h;
  *lo = l;
}

// B-frag (hi/lo) from an f32 feature row
__device__ __forceinline__ void load_xfrag(const float* xs, int kb, int lq,
                                           v8s* hi, v8s* lo) {
  v4f a = *reinterpret_cast<const v4f*>(xs + kb + 4 * lq);
  v4f b = *reinterpret_cast<const v4f*>(xs + kb + 16 + 4 * lq);
  split8(a, b, hi, lo);
}

// D blocks -> next-layer split B-frag with relu
__device__ __forceinline__ void chain_frag(v4f d0, v4f d1, v8s* hi, v8s* lo) {
  v4f a, b;
#pragma unroll
  for (int j = 0; j < 4; ++j) {
    a[j] = fmaxf(d0[j], 0.f);
    b[j] = fmaxf(d1[j], 0.f);
  }
  split8(a, b, hi, lo);
}

// ---------------- weight prequantization ----------------

__global__ void prew_kernel(const float* __restrict__ mW1,
                            const float* __restrict__ mW2,
                            const float* __restrict__ mW3,
                            const float* __restrict__ oW1,
                            const float* __restrict__ oW2,
                            const float* __restrict__ oW3,
                            short* __restrict__ wqs) {
  int lane = threadIdx.x;   // 64 threads, 1 block
  int l15 = lane & 15, lq = lane >> 4;
  v8s* wq = reinterpret_cast<v8s*>(wqs);
  v8s h, l;
#pragma unroll
  for (int t = 0; t < 2; ++t)
#pragma unroll
    for (int kc = 0; kc < 2; ++kc) {
      load_wfrag(mW1, HID, kc * 32, t * 16, lq, l15, &h, &l);
      wq[(t * 2 + kc) * 64 + lane] = h;
      wq[(4 + t * 2 + kc) * 64 + lane] = l;
      load_wfrag(mW1, HID, 64 + kc * 32, t * 16, lq, l15, &h, &l);
      wq[(8 + t * 2 + kc) * 64 + lane] = h;
      wq[(12 + t * 2 + kc) * 64 + lane] = l;
    }
#pragma unroll
  for (int t = 0; t < 2; ++t) {
    load_wfrag(mW2, HID, 0, t * 16, lq, l15, &h, &l);
    wq[(16 + t) * 64 + lane] = h;
    wq[(18 + t) * 64 + lane] = l;
  }
#pragma unroll
  for (int t = 0; t < 4; ++t) {
    load_wfrag(mW3, MSG, 0, t * 16, lq, l15, &h, &l);
    wq[(20 + t) * 64 + lane] = h;
    wq[(24 + t) * 64 + lane] = l;
  }
#pragma unroll
  for (int t = 0; t < 2; ++t)
#pragma unroll
    for (int kc = 0; kc < 4; ++kc) {
      load_wfrag(oW1, HID, kc * 32, t * 16, lq, l15, &h, &l);
      wq[(28 + t * 4 + kc) * 64 + lane] = h;
      wq[(36 + t * 4 + kc) * 64 + lane] = l;
    }
#pragma unroll
  for (int t = 0; t < 2; ++t) {
    load_wfrag(oW2, HID, 0, t * 16, lq, l15, &h, &l);
    wq[(44 + t) * 64 + lane] = h;
    wq[(46 + t) * 64 + lane] = l;
  }
#pragma unroll
  for (int t = 0; t < 4; ++t) {
    load_wfrag(oW3, SD, 0, t * 16, lq, l15, &h, &l);
    wq[(48 + t) * 64 + lane] = h;
    wq[(52 + t) * 64 + lane] = l;
  }
}

// ---------------- prep: h1d (f32, split-exact) + h1s (bf16) per node --------
// h1d[n] = mb1 + mW1[64:128]^T x[n]; h1s[n] = mW1[0:64]^T x[n] (no bias)
__global__ __launch_bounds__(256, 2) void prep_kernel(
    const float* __restrict__ x, const short* __restrict__ wqs,
    const float* __restrict__ mb1,
    float* __restrict__ h1d_buf, short* __restrict__ h1s_buf) {
  const int lane = threadIdx.x & 63;
  const int l15 = lane & 15;
  const int lq = lane >> 4;
  const int tile = (blockIdx.x * 256 + threadIdx.x) >> 6;
  if (tile >= NTILE) return;
  const v8s* wq = reinterpret_cast<const v8s*>(wqs);

  const int node = tile * 16 + l15;
  v4f d0, d1, s0 = {0.f, 0.f, 0.f, 0.f}, s1 = {0.f, 0.f, 0.f, 0.f};
#pragma unroll
  for (int q = 0; q < 4; ++q) {
    d0[q] = mb1[4 * lq + q];
    d1[q] = mb1[16 + 4 * lq + q];
  }
#pragma unroll
  for (int kc = 0; kc < 2; ++kc) {
    v8s xh, xl;
    load_xfrag(x + (size_t)node * SD, kc * 32, lq, &xh, &xl);
    d0 = mfma3(wq[(8 + kc) * 64 + lane], wq[(12 + kc) * 64 + lane], xh, xl, d0);
    d1 = mfma3(wq[(10 + kc) * 64 + lane], wq[(14 + kc) * 64 + lane], xh, xl, d1);
    s0 = mfma3(wq[(0 + kc) * 64 + lane], wq[(4 + kc) * 64 + lane], xh, xl, s0);
    s1 = mfma3(wq[(2 + kc) * 64 + lane], wq[(6 + kc) * 64 + lane], xh, xl, s1);
  }
  *reinterpret_cast<v4f*>(h1d_buf + (size_t)node * HID + 4 * lq) = d0;
  *reinterpret_cast<v4f*>(h1d_buf + (size_t)node * HID + 16 + 4 * lq) = d1;
  v4s q0, q1;
#pragma unroll
  for (int q = 0; q < 4; ++q) {
    q0[q] = f2bf(s0[q]);
    q1[q] = f2bf(s1[q]);
  }
  *reinterpret_cast<v4s*>(h1s_buf + (size_t)node * HID + 4 * lq) = q0;
  *reinterpret_cast<v4s*>(h1s_buf + (size_t)node * HID + 16 + 4 * lq) = q1;
}

// ---------------- CSR build: XCD-exclusive radix (4 kernels) ----------------

// A: per-(bin, WG) histogram
__global__ __launch_bounds__(256) void bin_count_kernel(
    const int* __restrict__ ei, int* __restrict__ gOff) {
  __shared__ int cnt[NBIN];
  const int w = blockIdx.x;
  for (int i = threadIdx.x; i < NBIN; i += 256) cnt[i] = 0;
  __syncthreads();
  const int e0 = w * EPW;
  const int e1 = (e0 + EPW < NE) ? e0 + EPW : NE;
  for (int e = e0 + threadIdx.x; e < e1; e += 256)
    atomicAdd(&cnt[ei[NE + e] >> 9], 1);
  __syncthreads();
  for (int i = threadIdx.x; i < NBIN; i += 256) gOff[i * NWG + w] = cnt[i];
}

// B: scan -> exclusive (bin, WG) offsets + bin starts
__global__ __launch_bounds__(256) void scan_bins_kernel(
    int* __restrict__ gOff, int* __restrict__ binStart) {
  __shared__ int tot[NBIN];
  const int b = threadIdx.x;
  if (b < NBIN) {
    int run = 0;
    for (int w = 0; w < NWG; ++w) {
      int v = gOff[b * NWG + w];
      gOff[b * NWG + w] = run;
      run += v;
    }
    tot[b] = run;
  }
  __syncthreads();
  if (threadIdx.x == 0) {
    int run = 0;
    for (int bb = 0; bb < NBIN; ++bb) {
      binStart[bb] = run;
      run += tot[bb];
    }
    binStart[NBIN] = run;   // == NE
  }
  __syncthreads();
  if (b < NBIN) {
    int base = binStart[b];
    for (int w = 0; w < NWG; ++w) gOff[b * NWG + w] += base;
  }
}

// C: scatter (src,dst) pairs into bin-grouped array; each (bin,WG) region is
// WG-exclusive -> every 32B sector written by ONE workgroup (no XCD amp)
__global__ __launch_bounds__(256) void bin_scatter_kernel(
    const int* __restrict__ ei, const int* __restrict__ gOff,
    int2* __restrict__ pairs) {
  __shared__ int cur[NBIN];
  const int w = blockIdx.x;
  for (int i = threadIdx.x; i < NBIN; i += 256) cur[i] = gOff[i * NWG + w];
  __syncthreads();
  const int e0 = w * EPW;
  const int e1 = (e0 + EPW < NE) ? e0 + EPW : NE;
  for (int e = e0 + threadIdx.x; e < e1; e += 256) {
    int s = ei[e];
    int d = ei[NE + e];
    int pos = atomicAdd(&cur[d >> 9], 1);
    pairs[pos] = make_int2(s, d);
  }
}

// D: one WG per bin: per-node hist+scan+scatter entirely in LDS
__global__ __launch_bounds__(512) void bin_csr_kernel(
    const int2* __restrict__ pairs, const int* __restrict__ binStart,
    int2* __restrict__ co, int* __restrict__ csr_src) {
  __shared__ int sh[BINSZ];
  __shared__ int cu[BINSZ];
  const int b = blockIdx.x;
  const int t = threadIdx.x;
  cu[t] = 0;
  __syncthreads();
  const int p0 = binStart[b], p1 = binStart[b + 1];
  for (int p = p0 + t; p < p1; p += BINSZ)
    atomicAdd(&cu[pairs[p].y & (BINSZ - 1)], 1);
  __syncthreads();
  const int v = cu[t];
  sh[t] = v;
  __syncthreads();
  for (int off = 1; off < BINSZ; off <<= 1) {
    int a = (t >= off) ? sh[t - off] : 0;
    __syncthreads();
    sh[t] += a;
    __syncthreads();
  }
  const int excl = sh[t] - v;
  const int node = b * BINSZ + t;
  if (node < NP) co[node] = make_int2(p0 + excl, v);
  cu[t] = excl;
  __syncthreads();
  for (int p = p0 + t; p < p1; p += BINSZ) {
    int2 pr = pairs[p];
    int loc = atomicAdd(&cu[pr.y & (BINSZ - 1)], 1);
    csr_src[p0 + loc] = pr.x;
  }
}

// ---------------- edge loop: h1s gather + layer2 only ----------------
__global__ __launch_bounds__(256, 4) void edge_mfma_kernel(
    const short* __restrict__ h1s, const float* __restrict__ h1d_buf,
    const short* __restrict__ wqs, const int2* __restrict__ co,
    const int* __restrict__ csr_src, const float* __restrict__ mb2,
    float* __restrict__ rsum) {
  const int lane = threadIdx.x & 63;
  const int l15 = lane & 15;
  const int lq = lane >> 4;
  const int wid = (blockIdx.x * 256 + threadIdx.x) >> 6;
  const int nw = gridDim.x * 4;
  const v8s* wq = reinterpret_cast<const v8s*>(wqs);

  const v8s w2h0 = wq[16 * 64 + lane], w2h1 = wq[17 * 64 + lane];
  const v8s w2l0 = wq[18 * 64 + lane], w2l1 = wq[19 * 64 + lane];
  v4f bb0, bb1;
#pragma unroll
  for (int q = 0; q < 4; ++q) {
    bb0[q] = mb2[4 * lq + q];
    bb1[q] = mb2[16 + 4 * lq + q];
  }

  for (int n = wid; n < NP; n += nw) {
    const int2 c = co[n];
    const int off = c.x, cnt = c.y;
    const int ng = (cnt + 15) >> 4;

    const v4f h1d0 = *reinterpret_cast<const v4f*>(h1d_buf + (size_t)n * HID + 4 * lq);
    const v4f h1d1 = *reinterpret_cast<const v4f*>(h1d_buf + (size_t)n * HID + 16 + 4 * lq);

    v4f r0 = {0.f, 0.f, 0.f, 0.f}, r1 = {0.f, 0.f, 0.f, 0.f};

    int rem = cnt;
    bool vcur = l15 < rem;
    int scur = vcur ? csr_src[off + l15] : 0;
    v4s ca = *reinterpret_cast<const v4s*>(h1s + (size_t)scur * HID + 4 * lq);
    v4s cb = *reinterpret_cast<const v4s*>(h1s + (size_t)scur * HID + 16 + 4 * lq);

    for (int g = 0; g < ng; ++g) {
      // prefetch next group's h1s rows
      int rem2 = rem - 16;
      bool vnxt = l15 < rem2;
      int snxt = vnxt ? csr_src[off + (g + 1) * 16 + l15] : 0;
      v4s na = *reinterpret_cast<const v4s*>(h1s + (size_t)snxt * HID + 4 * lq);
      v4s nb = *reinterpret_cast<const v4s*>(h1s + (size_t)snxt * HID + 16 + 4 * lq);

      // h1 = h1s[src] + h1d[dst] in f32
      v4f d0, d1;
#pragma unroll
      for (int q = 0; q < 4; ++q) {
        d0[q] = h1d0[q] + bf2f(ca[q]);
        d1[q] = h1d1[q] + bf2f(cb[q]);
      }

      // layer 2 (split P, node-coherent)
      v8s ph, pl;
      chain_frag(d0, d1, &ph, &pl);
      v4f e0 = bb0, e1 = bb1;
      e0 = mfma3(w2h0, w2l0, ph, pl, e0);
      e1 = mfma3(w2h1, w2l1, ph, pl, e1);

      if (vcur) {
#pragma unroll
        for (int j = 0; j < 4; ++j) {
          r0[j] += fmaxf(e0[j], 0.f);
          r1[j] += fmaxf(e1[j], 0.f);
        }
      }
      ca = na;
      cb = nb;
      vcur = vnxt;
      rem = rem2;
    }

    // reduce relu-sums over the 16 slot-columns
#pragma unroll
    for (int j = 0; j < 4; ++j) {
      float a = r0[j], b = r1[j];
      a += __shfl_xor(a, 1); a += __shfl_xor(a, 2);
      a += __shfl_xor(a, 4); a += __shfl_xor(a, 8);
      b += __shfl_xor(b, 1); b += __shfl_xor(b, 2);
      b += __shfl_xor(b, 4); b += __shfl_xor(b, 8);
      r0[j] = a; r1[j] = b;
    }
    if (l15 == 0) {
      *reinterpret_cast<v4f*>(rsum + (size_t)n * HID + 4 * lq) = r0;
      *reinterpret_cast<v4f*>(rsum + (size_t)n * HID + 16 + 4 * lq) = r1;
    }
  }
}

// ---------------- fused tail: edge layer3 + full node MLP, 16 nodes/wave ----
__global__ __launch_bounds__(256, 2) void fused_tail_kernel(
    const float* __restrict__ x, const short* __restrict__ wqs,
    const float* __restrict__ rsum, const int2* __restrict__ co,
    const float* __restrict__ mb3,
    const float* __restrict__ ob1, const float* __restrict__ ob2,
    const float* __restrict__ ob3,
    float* __restrict__ out) {
  const int lane = threadIdx.x & 63;
  const int l15 = lane & 15;
  const int lq = lane >> 4;
  const int tile = (blockIdx.x * 256 + threadIdx.x) >> 6;
  if (tile >= NTILE) return;
  const v8s* wq = reinterpret_cast<const v8s*>(wqs);

  const int node = tile * 16 + l15;
  const float fc = (float)co[node].y;

  // edge layer 3: msg = mW3^T r + fc*mb3
  v4f ra = *reinterpret_cast<const v4f*>(rsum + (size_t)node * HID + 4 * lq);
  v4f rb = *reinterpret_cast<const v4f*>(rsum + (size_t)node * HID + 16 + 4 * lq);
  v8s bh, bl;
  split8(ra, rb, &bh, &bl);

  v4f m[4];
#pragma unroll
  for (int t = 0; t < 4; ++t) {
    v4f c = {0.f, 0.f, 0.f, 0.f};
    c = mfma3(wq[(20 + t) * 64 + lane], wq[(24 + t) * 64 + lane], bh, bl, c);
#pragma unroll
    for (int q = 0; q < 4; ++q) c[q] += fc * mb3[t * 16 + 4 * lq + q];
    m[t] = c;
  }

  // node layer 1 on [x || msg]
  v4f d0, d1;
#pragma unroll
  for (int q = 0; q < 4; ++q) {
    d0[q] = ob1[4 * lq + q];
    d1[q] = ob1[16 + 4 * lq + q];
  }
#pragma unroll
  for (int kc = 0; kc < 2; ++kc) {
    v8s xh, xl;
    load_xfrag(x + (size_t)node * SD, kc * 32, lq, &xh, &xl);
    d0 = mfma3(wq[(28 + kc) * 64 + lane], wq[(36 + kc) * 64 + lane], xh, xl, d0);
    d1 = mfma3(wq[(32 + kc) * 64 + lane], wq[(40 + kc) * 64 + lane], xh, xl, d1);
  }
#pragma unroll
  for (int kc = 0; kc < 2; ++kc) {
    v8s mh, ml;
    split8(m[kc * 2], m[kc * 2 + 1], &mh, &ml);
    d0 = mfma3(wq[(30 + kc) * 64 + lane], wq[(38 + kc) * 64 + lane], mh, ml, d0);
    d1 = mfma3(wq[(34 + kc) * 64 + lane], wq[(42 + kc) * 64 + lane], mh, ml, d1);
  }

  // node layer 2
  v8s ph, pl;
  chain_frag(d0, d1, &ph, &pl);
  v4f e0, e1;
#pragma unroll
  for (int q = 0; q < 4; ++q) {
    e0[q] = ob2[4 * lq + q];
    e1[q] = ob2[16 + 4 * lq + q];
  }
  e0 = mfma3(wq[44 * 64 + lane], wq[46 * 64 + lane], ph, pl, e0);
  e1 = mfma3(wq[45 * 64 + lane], wq[47 * 64 + lane], ph, pl, e1);

  // node layer 3 -> out
  v8s rh, rl;
  chain_frag(e0, e1, &rh, &rl);
  float* orow = out + (size_t)node * SD;
#pragma unroll
  for (int t = 0; t < 4; ++t) {
    v4f c;
#pragma unroll
    for (int q = 0; q < 4; ++q) c[q] = ob3[t * 16 + 4 * lq + q];
    c = mfma3(wq[(48 + t) * 64 + lane], wq[(52 + t) * 64 + lane], rh, rl, c);
    *reinterpret_cast<v4f*>(orow + t * 16 + 4 * lq) = c;
  }
}

extern "C" void kernel_launch(void* const* d_in, const int* in_sizes, int n_in,
                              void* d_out, int out_size, void* d_ws,
                              size_t ws_size, hipStream_t stream) {
  const float* x = (const float*)d_in[0];
  const int* ei = (const int*)d_in[1];
  const float* mW1 = (const float*)d_in[2];
  const float* mb1 = (const float*)d_in[3];
  const float* mW2 = (const float*)d_in[4];
  const float* mb2 = (const float*)d_in[5];
  const float* mW3 = (const float*)d_in[6];
  const float* mb3 = (const float*)d_in[7];
  const float* oW1 = (const float*)d_in[8];
  const float* ob1 = (const float*)d_in[9];
  const float* oW2 = (const float*)d_in[10];
  const float* ob2 = (const float*)d_in[11];
  const float* oW3 = (const float*)d_in[12];
  const float* ob3 = (const float*)d_in[13];
  float* out = (float*)d_out;

  // d_out doubles as scratch for h1d (12.8MB f32) + h1s (6.4MB bf16): both are
  // fully consumed by edge_mfma before fused_tail overwrites out.
  float* h1d_buf = (float*)d_out;
  short* h1s_buf = (short*)((char*)d_out + (size_t)NP * HID * 4);

  // ws layout (~20.2MB; R8 proved ws >= 33.3MB):
  // wq | gOff | binStart | co | csr_src | pairs (rsum aliases pairs after D)
  char* p = (char*)d_ws;
  short* wqs = (short*)p;            p += (size_t)WQ_FRAGS * 64 * 16;
  int* gOff = (int*)p;               p += (size_t)NBIN * NWG * 4;
  int* binStart = (int*)p;           p += 200 * 4;
  int2* co = (int2*)p;               p += (size_t)NP_PAD * 8;
  int* csr_src = (int*)p;            p += (size_t)NE * 4;
  int2* pairs = (int2*)p;
  float* rsum = (float*)pairs;       // NE*8 == NP*HID*4 == 12.8MB

  prew_kernel<<<1, 64, 0, stream>>>(mW1, mW2, mW3, oW1, oW2, oW3, wqs);

  const int tile_blocks = (NTILE + 3) / 4;
  prep_kernel<<<tile_blocks, 256, 0, stream>>>(x, wqs, mb1, h1d_buf, h1s_buf);

  bin_count_kernel<<<NWG, 256, 0, stream>>>(ei, gOff);
  scan_bins_kernel<<<1, 256, 0, stream>>>(gOff, binStart);
  bin_scatter_kernel<<<NWG, 256, 0, stream>>>(ei, gOff, pairs);
  bin_csr_kernel<<<NBIN, 512, 0, stream>>>(pairs, binStart, co, csr_src);

  edge_mfma_kernel<<<2048, 256, 0, stream>>>(
      h1s_buf, h1d_buf, wqs, co, csr_src, mb2, rsum);

  fused_tail_kernel<<<tile_blocks, 256, 0, stream>>>(
      x, wqs, rsum, co, mb3, ob1, ob2, ob3, out);
}

// Round 10
// 158.121 us; speedup vs baseline: 35.4127x; 1.0968x over previous
//
#include <hip/hip_runtime.h>

#define NP 100000
#define NE 1600000
#define SD 64      // STATE_DIM
#define HID 32
#define MSG 64
#define NP_PAD 100352
#define NTILE (NP / 16)          // 6250
#define TILE_BLOCKS ((NTILE + 3) / 4)     // 1563
#define BINSZ 512
#define NBIN ((NP + BINSZ - 1) / BINSZ)   // 196
#define EPW 8192
#define NWG ((NE + EPW - 1) / EPW)        // 196

typedef float v4f __attribute__((ext_vector_type(4)));
typedef short v4s __attribute__((ext_vector_type(4)));
typedef short v8s __attribute__((ext_vector_type(8)));
typedef __bf16 v8bf __attribute__((ext_vector_type(8)));

// weight-frag ids (each frag = 64 lanes x v8s = 1 KiB):
// edge MLP: 0-3 w1s hi [t*2+kc], 4-7 w1s lo, 8-11 w1d hi [t*2+kc], 12-15 w1d lo,
//           16-17 w2 hi[t], 18-19 w2 lo, 20-23 w3 hi[t], 24-27 w3 lo
// node MLP: 28-35 oW1 hi [t*4+kc], 36-43 oW1 lo, 44-45 oW2 hi, 46-47 oW2 lo,
//           48-51 oW3 hi[t], 52-55 oW3 lo
#define WQ_FRAGS 56

__device__ __forceinline__ v4f MFMA32(v8s a, v8s b, v4f c) {
  return __builtin_amdgcn_mfma_f32_16x16x32_bf16(
      __builtin_bit_cast(v8bf, a), __builtin_bit_cast(v8bf, b), c, 0, 0, 0);
}

__device__ __forceinline__ short f2bf(float f) {   // HW RNE cvt
  return __builtin_bit_cast(short, (__bf16)f);
}
__device__ __forceinline__ float bf2f(short s) {
  unsigned u = ((unsigned)(unsigned short)s) << 16;
  return __builtin_bit_cast(float, u);
}

// 3-term split-bf16 product: C += Ah*Bh + Ah*Bl + Al*Bh (error ~2^-17 rel)
__device__ __forceinline__ v4f mfma3(v8s ah, v8s al, v8s bh, v8s bl, v4f c) {
  c = MFMA32(al, bh, c);
  c = MFMA32(ah, bl, c);
  c = MFMA32(ah, bh, c);
  return c;
}

// A-frag (hi/lo) from row-major W[K][ld]: A[m][k] = W[k][m0+l15]
__device__ __forceinline__ void load_wfrag(const float* __restrict__ W, int ld,
                                           int kb, int m0, int lq, int l15,
                                           v8s* hi, v8s* lo) {
  v8s h, l;
#pragma unroll
  for (int j = 0; j < 8; ++j) {
    int k = kb + ((j < 4) ? (4 * lq + j) : (16 + 4 * lq + (j - 4)));
    float v = W[k * ld + m0 + l15];
    short hb = f2bf(v);
    h[j] = hb;
    l[j] = f2bf(v - bf2f(hb));
  }
  *hi = h;
  *lo = l;
}

// split two v4f halves into one split B-frag (no relu)
__device__ __forceinline__ void split8(v4f a, v4f b, v8s* hi, v8s* lo) {
  v8s h, l;
#pragma unroll
  for (int j = 0; j < 4; ++j) {
    short ha = f2bf(a[j]); h[j] = ha; l[j] = f2bf(a[j] - bf2f(ha));
    short hb = f2bf(b[j]); h[j + 4] = hb; l[j + 4] = f2bf(b[j] - bf2f(hb));
  }
  *hi = h;
  *lo = l;
}

// B-frag (hi/lo) from an f32 feature row
__device__ __forceinline__ void load_xfrag(const float* xs, int kb, int lq,
                                           v8s* hi, v8s* lo) {
  v4f a = *reinterpret_cast<const v4f*>(xs + kb + 4 * lq);
  v4f b = *reinterpret_cast<const v4f*>(xs + kb + 16 + 4 * lq);
  split8(a, b, hi, lo);
}

// D blocks -> next-layer split B-frag with relu
__device__ __forceinline__ void chain_frag(v4f d0, v4f d1, v8s* hi, v8s* lo) {
  v4f a, b;
#pragma unroll
  for (int j = 0; j < 4; ++j) {
    a[j] = fmaxf(d0[j], 0.f);
    b[j] = fmaxf(d1[j], 0.f);
  }
  split8(a, b, hi, lo);
}

// ---------------- setup: bin_count (blocks 0..NWG-1) | prew (block NWG) |
//                  prep (blocks NWG+1 ..) -- all independent ----------------
__global__ __launch_bounds__(256, 2) void setup_kernel(
    const float* __restrict__ x, const int* __restrict__ ei,
    const float* __restrict__ mW1, const float* __restrict__ mb1,
    const float* __restrict__ mW2, const float* __restrict__ mW3,
    const float* __restrict__ oW1, const float* __restrict__ oW2,
    const float* __restrict__ oW3,
    int* __restrict__ gOff, short* __restrict__ wqs,
    float* __restrict__ h1d_buf, short* __restrict__ h1s_buf) {
  __shared__ int cnt[NBIN];
  const int blk = blockIdx.x;

  if (blk < NWG) {
    // ---- per-(bin, WG) histogram ----
    for (int i = threadIdx.x; i < NBIN; i += 256) cnt[i] = 0;
    __syncthreads();
    const int e0 = blk * EPW;
    const int e1 = (e0 + EPW < NE) ? e0 + EPW : NE;
    for (int e = e0 + threadIdx.x; e < e1; e += 256)
      atomicAdd(&cnt[ei[NE + e] >> 9], 1);
    __syncthreads();
    for (int i = threadIdx.x; i < NBIN; i += 256) gOff[i * NWG + blk] = cnt[i];
    return;
  }

  const int lane = threadIdx.x & 63;
  const int l15 = lane & 15;
  const int lq = lane >> 4;

  if (blk == NWG) {
    // ---- weight prequantization (64 threads) ----
    if (threadIdx.x >= 64) return;
    v8s* wq = reinterpret_cast<v8s*>(wqs);
    v8s h, l;
#pragma unroll
    for (int t = 0; t < 2; ++t)
#pragma unroll
      for (int kc = 0; kc < 2; ++kc) {
        load_wfrag(mW1, HID, kc * 32, t * 16, lq, l15, &h, &l);
        wq[(t * 2 + kc) * 64 + lane] = h;
        wq[(4 + t * 2 + kc) * 64 + lane] = l;
        load_wfrag(mW1, HID, 64 + kc * 32, t * 16, lq, l15, &h, &l);
        wq[(8 + t * 2 + kc) * 64 + lane] = h;
        wq[(12 + t * 2 + kc) * 64 + lane] = l;
      }
#pragma unroll
    for (int t = 0; t < 2; ++t) {
      load_wfrag(mW2, HID, 0, t * 16, lq, l15, &h, &l);
      wq[(16 + t) * 64 + lane] = h;
      wq[(18 + t) * 64 + lane] = l;
    }
#pragma unroll
    for (int t = 0; t < 4; ++t) {
      load_wfrag(mW3, MSG, 0, t * 16, lq, l15, &h, &l);
      wq[(20 + t) * 64 + lane] = h;
      wq[(24 + t) * 64 + lane] = l;
    }
#pragma unroll
    for (int t = 0; t < 2; ++t)
#pragma unroll
      for (int kc = 0; kc < 4; ++kc) {
        load_wfrag(oW1, HID, kc * 32, t * 16, lq, l15, &h, &l);
        wq[(28 + t * 4 + kc) * 64 + lane] = h;
        wq[(36 + t * 4 + kc) * 64 + lane] = l;
      }
#pragma unroll
    for (int t = 0; t < 2; ++t) {
      load_wfrag(oW2, HID, 0, t * 16, lq, l15, &h, &l);
      wq[(44 + t) * 64 + lane] = h;
      wq[(46 + t) * 64 + lane] = l;
    }
#pragma unroll
    for (int t = 0; t < 4; ++t) {
      load_wfrag(oW3, SD, 0, t * 16, lq, l15, &h, &l);
      wq[(48 + t) * 64 + lane] = h;
      wq[(52 + t) * 64 + lane] = l;
    }
    return;
  }

  // ---- prep: h1d (f32, split-exact) + h1s (bf16) per node, 16 nodes/wave.
  // Weights loaded from f32 directly (L2-hot broadcast) -> no prew dependency.
  const int tile = ((blk - NWG - 1) * 256 + (int)threadIdx.x) >> 6;
  if (tile >= NTILE) return;
  const int node = tile * 16 + l15;

  v4f d0, d1, s0 = {0.f, 0.f, 0.f, 0.f}, s1 = {0.f, 0.f, 0.f, 0.f};
#pragma unroll
  for (int q = 0; q < 4; ++q) {
    d0[q] = mb1[4 * lq + q];
    d1[q] = mb1[16 + 4 * lq + q];
  }
#pragma unroll
  for (int kc = 0; kc < 2; ++kc) {
    v8s xh, xl, wh, wl;
    load_xfrag(x + (size_t)node * SD, kc * 32, lq, &xh, &xl);
    load_wfrag(mW1, HID, 64 + kc * 32, 0, lq, l15, &wh, &wl);
    d0 = mfma3(wh, wl, xh, xl, d0);
    load_wfrag(mW1, HID, 64 + kc * 32, 16, lq, l15, &wh, &wl);
    d1 = mfma3(wh, wl, xh, xl, d1);
    load_wfrag(mW1, HID, kc * 32, 0, lq, l15, &wh, &wl);
    s0 = mfma3(wh, wl, xh, xl, s0);
    load_wfrag(mW1, HID, kc * 32, 16, lq, l15, &wh, &wl);
    s1 = mfma3(wh, wl, xh, xl, s1);
  }
  *reinterpret_cast<v4f*>(h1d_buf + (size_t)node * HID + 4 * lq) = d0;
  *reinterpret_cast<v4f*>(h1d_buf + (size_t)node * HID + 16 + 4 * lq) = d1;
  v4s q0, q1;
#pragma unroll
  for (int q = 0; q < 4; ++q) {
    q0[q] = f2bf(s0[q]);
    q1[q] = f2bf(s1[q]);
  }
  *reinterpret_cast<v4s*>(h1s_buf + (size_t)node * HID + 4 * lq) = q0;
  *reinterpret_cast<v4s*>(h1s_buf + (size_t)node * HID + 16 + 4 * lq) = q1;
}

// ---------------- CSR build (rest of the XCD-exclusive radix) ----------------

// scan -> exclusive (bin, WG) offsets + bin starts
__global__ __launch_bounds__(256) void scan_bins_kernel(
    int* __restrict__ gOff, int* __restrict__ binStart) {
  __shared__ int tot[NBIN];
  const int b = threadIdx.x;
  if (b < NBIN) {
    int run = 0;
    for (int w = 0; w < NWG; ++w) {
      int v = gOff[b * NWG + w];
      gOff[b * NWG + w] = run;
      run += v;
    }
    tot[b] = run;
  }
  __syncthreads();
  if (threadIdx.x == 0) {
    int run = 0;
    for (int bb = 0; bb < NBIN; ++bb) {
      binStart[bb] = run;
      run += tot[bb];
    }
    binStart[NBIN] = run;   // == NE
  }
  __syncthreads();
  if (b < NBIN) {
    int base = binStart[b];
    for (int w = 0; w < NWG; ++w) gOff[b * NWG + w] += base;
  }
}

// scatter (src,dst) pairs into bin-grouped array; (bin,WG) regions exclusive
__global__ __launch_bounds__(256) void bin_scatter_kernel(
    const int* __restrict__ ei, const int* __restrict__ gOff,
    int2* __restrict__ pairs) {
  __shared__ int cur[NBIN];
  const int w = blockIdx.x;
  for (int i = threadIdx.x; i < NBIN; i += 256) cur[i] = gOff[i * NWG + w];
  __syncthreads();
  const int e0 = w * EPW;
  const int e1 = (e0 + EPW < NE) ? e0 + EPW : NE;
  for (int e = e0 + threadIdx.x; e < e1; e += 256) {
    int s = ei[e];
    int d = ei[NE + e];
    int pos = atomicAdd(&cur[d >> 9], 1);
    pairs[pos] = make_int2(s, d);
  }
}

// one WG per bin: per-node hist+scan+scatter entirely in LDS
__global__ __launch_bounds__(512) void bin_csr_kernel(
    const int2* __restrict__ pairs, const int* __restrict__ binStart,
    int2* __restrict__ co, int* __restrict__ csr_src) {
  __shared__ int sh[BINSZ];
  __shared__ int cu[BINSZ];
  const int b = blockIdx.x;
  const int t = threadIdx.x;
  cu[t] = 0;
  __syncthreads();
  const int p0 = binStart[b], p1 = binStart[b + 1];
  for (int p = p0 + t; p < p1; p += BINSZ)
    atomicAdd(&cu[pairs[p].y & (BINSZ - 1)], 1);
  __syncthreads();
  const int v = cu[t];
  sh[t] = v;
  __syncthreads();
  for (int off = 1; off < BINSZ; off <<= 1) {
    int a = (t >= off) ? sh[t - off] : 0;
    __syncthreads();
    sh[t] += a;
    __syncthreads();
  }
  const int excl = sh[t] - v;
  const int node = b * BINSZ + t;
  if (node < NP) co[node] = make_int2(p0 + excl, v);
  cu[t] = excl;
  __syncthreads();
  for (int p = p0 + t; p < p1; p += BINSZ) {
    int2 pr = pairs[p];
    int loc = atomicAdd(&cu[pr.y & (BINSZ - 1)], 1);
    csr_src[p0 + loc] = pr.x;
  }
}

// ---------------- edge loop: depth-2 pipelined gather + layer2 ----------------
__global__ __launch_bounds__(256, 4) void edge_mfma_kernel(
    const short* __restrict__ h1s, const float* __restrict__ h1d_buf,
    const short* __restrict__ wqs, const int2* __restrict__ co,
    const int* __restrict__ csr_src, const float* __restrict__ mb2,
    float* __restrict__ rsum) {
  const int lane = threadIdx.x & 63;
  const int l15 = lane & 15;
  const int lq = lane >> 4;
  const int wid = (blockIdx.x * 256 + threadIdx.x) >> 6;
  const int nw = gridDim.x * 4;
  const v8s* wq = reinterpret_cast<const v8s*>(wqs);

  const v8s w2h0 = wq[16 * 64 + lane], w2h1 = wq[17 * 64 + lane];
  const v8s w2l0 = wq[18 * 64 + lane], w2l1 = wq[19 * 64 + lane];
  v4f bb0, bb1;
#pragma unroll
  for (int q = 0; q < 4; ++q) {
    bb0[q] = mb2[4 * lq + q];
    bb1[q] = mb2[16 + 4 * lq + q];
  }

  for (int n = wid; n < NP; n += nw) {
    const int2 c = co[n];
    const int off = c.x, cnt = c.y;
    const int ng = (cnt + 15) >> 4;

    const v4f h1d0 = *reinterpret_cast<const v4f*>(h1d_buf + (size_t)n * HID + 4 * lq);
    const v4f h1d1 = *reinterpret_cast<const v4f*>(h1d_buf + (size_t)n * HID + 16 + 4 * lq);

    v4f r0 = {0.f, 0.f, 0.f, 0.f}, r1 = {0.f, 0.f, 0.f, 0.f};

    // ---- depth-2 pipeline prologue: groups 0 and 1 in flight ----
    int sa = (l15 < cnt) ? csr_src[off + l15] : 0;
    v4s a0 = *reinterpret_cast<const v4s*>(h1s + (size_t)sa * HID + 4 * lq);
    v4s b0 = *reinterpret_cast<const v4s*>(h1s + (size_t)sa * HID + 16 + 4 * lq);
    int sb = (l15 < cnt - 16) ? csr_src[off + 16 + l15] : 0;
    v4s a1 = *reinterpret_cast<const v4s*>(h1s + (size_t)sb * HID + 4 * lq);
    v4s b1 = *reinterpret_cast<const v4s*>(h1s + (size_t)sb * HID + 16 + 4 * lq);

    int rem = cnt;
    for (int g = 0; g < ng; ++g) {
      // issue g+2 index load first (covered by this group's compute)
      int sc = (l15 < rem - 32) ? csr_src[off + (g + 2) * 16 + l15] : 0;

      // h1 = h1s[src] + h1d[dst] in f32
      v4f d0, d1;
#pragma unroll
      for (int q = 0; q < 4; ++q) {
        d0[q] = h1d0[q] + bf2f(a0[q]);
        d1[q] = h1d1[q] + bf2f(b0[q]);
      }

      // layer 2 (split P, node-coherent)
      v8s ph, pl;
      chain_frag(d0, d1, &ph, &pl);
      v4f e0 = bb0, e1 = bb1;
      e0 = mfma3(w2h0, w2l0, ph, pl, e0);
      e1 = mfma3(w2h1, w2l1, ph, pl, e1);

      if (l15 < rem) {
#pragma unroll
        for (int j = 0; j < 4; ++j) {
          r0[j] += fmaxf(e0[j], 0.f);
          r1[j] += fmaxf(e1[j], 0.f);
        }
      }

      // issue g+2 gather (lands during group g+1's compute)
      v4s a2 = *reinterpret_cast<const v4s*>(h1s + (size_t)sc * HID + 4 * lq);
      v4s b2 = *reinterpret_cast<const v4s*>(h1s + (size_t)sc * HID + 16 + 4 * lq);

      a0 = a1; b0 = b1;
      a1 = a2; b1 = b2;
      rem -= 16;
    }

    // reduce relu-sums over the 16 slot-columns
#pragma unroll
    for (int j = 0; j < 4; ++j) {
      float a = r0[j], b = r1[j];
      a += __shfl_xor(a, 1); a += __shfl_xor(a, 2);
      a += __shfl_xor(a, 4); a += __shfl_xor(a, 8);
      b += __shfl_xor(b, 1); b += __shfl_xor(b, 2);
      b += __shfl_xor(b, 4); b += __shfl_xor(b, 8);
      r0[j] = a; r1[j] = b;
    }
    if (l15 == 0) {
      *reinterpret_cast<v4f*>(rsum + (size_t)n * HID + 4 * lq) = r0;
      *reinterpret_cast<v4f*>(rsum + (size_t)n * HID + 16 + 4 * lq) = r1;
    }
  }
}

// ---------------- fused tail: edge layer3 + full node MLP, 16 nodes/wave ----
__global__ __launch_bounds__(256, 2) void fused_tail_kernel(
    const float* __restrict__ x, const short* __restrict__ wqs,
    const float* __restrict__ rsum, const int2* __restrict__ co,
    const float* __restrict__ mb3,
    const float* __restrict__ ob1, const float* __restrict__ ob2,
    const float* __restrict__ ob3,
    float* __restrict__ out) {
  const int lane = threadIdx.x & 63;
  const int l15 = lane & 15;
  const int lq = lane >> 4;
  const int tile = (blockIdx.x * 256 + threadIdx.x) >> 6;
  if (tile >= NTILE) return;
  const v8s* wq = reinterpret_cast<const v8s*>(wqs);

  const int node = tile * 16 + l15;
  const float fc = (float)co[node].y;

  // edge layer 3: msg = mW3^T r + fc*mb3
  v4f ra = *reinterpret_cast<const v4f*>(rsum + (size_t)node * HID + 4 * lq);
  v4f rb = *reinterpret_cast<const v4f*>(rsum + (size_t)node * HID + 16 + 4 * lq);
  v8s bh, bl;
  split8(ra, rb, &bh, &bl);

  v4f m[4];
#pragma unroll
  for (int t = 0; t < 4; ++t) {
    v4f c = {0.f, 0.f, 0.f, 0.f};
    c = mfma3(wq[(20 + t) * 64 + lane], wq[(24 + t) * 64 + lane], bh, bl, c);
#pragma unroll
    for (int q = 0; q < 4; ++q) c[q] += fc * mb3[t * 16 + 4 * lq + q];
    m[t] = c;
  }

  // node layer 1 on [x || msg]
  v4f d0, d1;
#pragma unroll
  for (int q = 0; q < 4; ++q) {
    d0[q] = ob1[4 * lq + q];
    d1[q] = ob1[16 + 4 * lq + q];
  }
#pragma unroll
  for (int kc = 0; kc < 2; ++kc) {
    v8s xh, xl;
    load_xfrag(x + (size_t)node * SD, kc * 32, lq, &xh, &xl);
    d0 = mfma3(wq[(28 + kc) * 64 + lane], wq[(36 + kc) * 64 + lane], xh, xl, d0);
    d1 = mfma3(wq[(32 + kc) * 64 + lane], wq[(40 + kc) * 64 + lane], xh, xl, d1);
  }
#pragma unroll
  for (int kc = 0; kc < 2; ++kc) {
    v8s mh, ml;
    split8(m[kc * 2], m[kc * 2 + 1], &mh, &ml);
    d0 = mfma3(wq[(30 + kc) * 64 + lane], wq[(38 + kc) * 64 + lane], mh, ml, d0);
    d1 = mfma3(wq[(34 + kc) * 64 + lane], wq[(42 + kc) * 64 + lane], mh, ml, d1);
  }

  // node layer 2
  v8s ph, pl;
  chain_frag(d0, d1, &ph, &pl);
  v4f e0, e1;
#pragma unroll
  for (int q = 0; q < 4; ++q) {
    e0[q] = ob2[4 * lq + q];
    e1[q] = ob2[16 + 4 * lq + q];
  }
  e0 = mfma3(wq[44 * 64 + lane], wq[46 * 64 + lane], ph, pl, e0);
  e1 = mfma3(wq[45 * 64 + lane], wq[47 * 64 + lane], ph, pl, e1);

  // node layer 3 -> out
  v8s rh, rl;
  chain_frag(e0, e1, &rh, &rl);
  float* orow = out + (size_t)node * SD;
#pragma unroll
  for (int t = 0; t < 4; ++t) {
    v4f c;
#pragma unroll
    for (int q = 0; q < 4; ++q) c[q] = ob3[t * 16 + 4 * lq + q];
    c = mfma3(wq[(48 + t) * 64 + lane], wq[(52 + t) * 64 + lane], rh, rl, c);
    *reinterpret_cast<v4f*>(orow + t * 16 + 4 * lq) = c;
  }
}

extern "C" void kernel_launch(void* const* d_in, const int* in_sizes, int n_in,
                              void* d_out, int out_size, void* d_ws,
                              size_t ws_size, hipStream_t stream) {
  const float* x = (const float*)d_in[0];
  const int* ei = (const int*)d_in[1];
  const float* mW1 = (const float*)d_in[2];
  const float* mb1 = (const float*)d_in[3];
  const float* mW2 = (const float*)d_in[4];
  const float* mb2 = (const float*)d_in[5];
  const float* mW3 = (const float*)d_in[6];
  const float* mb3 = (const float*)d_in[7];
  const float* oW1 = (const float*)d_in[8];
  const float* ob1 = (const float*)d_in[9];
  const float* oW2 = (const float*)d_in[10];
  const float* ob2 = (const float*)d_in[11];
  const float* oW3 = (const float*)d_in[12];
  const float* ob3 = (const float*)d_in[13];
  float* out = (float*)d_out;

  // d_out doubles as scratch for h1d (12.8MB f32) + h1s (6.4MB bf16): both are
  // fully consumed by edge_mfma before fused_tail overwrites out.
  float* h1d_buf = (float*)d_out;
  short* h1s_buf = (short*)((char*)d_out + (size_t)NP * HID * 4);

  // ws layout (~20.2MB; proven ws >= 33.3MB):
  // wq | gOff | binStart | co | csr_src | pairs (rsum aliases pairs)
  char* p = (char*)d_ws;
  short* wqs = (short*)p;            p += (size_t)WQ_FRAGS * 64 * 16;
  int* gOff = (int*)p;               p += (size_t)NBIN * NWG * 4;
  int* binStart = (int*)p;           p += 200 * 4;
  int2* co = (int2*)p;               p += (size_t)NP_PAD * 8;
  int* csr_src = (int*)p;            p += (size_t)NE * 4;
  int2* pairs = (int2*)p;
  float* rsum = (float*)pairs;       // NE*8 == NP*HID*4 == 12.8MB

  setup_kernel<<<NWG + 1 + TILE_BLOCKS, 256, 0, stream>>>(
      x, ei, mW1, mb1, mW2, mW3, oW1, oW2, oW3, gOff, wqs, h1d_buf, h1s_buf);

  scan_bins_kernel<<<1, 256, 0, stream>>>(gOff, binStart);
  bin_scatter_kernel<<<NWG, 256, 0, stream>>>(ei, gOff, pairs);
  bin_csr_kernel<<<NBIN, 512, 0, stream>>>(pairs, binStart, co, csr_src);

  edge_mfma_kernel<<<2048, 256, 0, stream>>>(
      h1s_buf, h1d_buf, wqs, co, csr_src, mb2, rsum);

  fused_tail_kernel<<<TILE_BLOCKS, 256, 0, stream>>>(
      x, wqs, rsum, co, mb3, ob1, ob2, ob3, out);
}